// Round 2
// baseline (639.758 us; speedup 1.0000x reference)
//
#include <hip/hip_runtime.h>
#include <hip/hip_bf16.h>
#include <math.h>

// GAE on MI355X. N=16384 nodes, E=524288 edges.
// R2: edge/heads weights via uniform global loads (s_load, no LDS broadcast),
// bf16 z gathers in edge kernel, agg loop unrolled x4, nontemporal stores for
// the 1.1 GB adj + 33 MB edge-feature write streams.

constexpr int kN = 16384;
constexpr int kE = 524288;
constexpr float kEps = 1e-5f;

typedef __attribute__((ext_vector_type(8))) short short8v;   // 8 x bf16
typedef __attribute__((ext_vector_type(4))) float f32x4;

__device__ inline float bf2f(short u) {
  return __uint_as_float(((unsigned)(unsigned short)u) << 16);
}

// ---------------------------------------------------------------- utility
__global__ void zero_kernel(int* counts, float* sums1, float* sums2) {
  int i = blockIdx.x * 256 + threadIdx.x;
  if (i < kN) counts[i] = 0;
  if (i < 256) sums1[i] = 0.f;
  if (i < 128) sums2[i] = 0.f;
}

__global__ void hist_kernel(const int* __restrict__ dst, int* __restrict__ counts) {
  int e = blockIdx.x * 256 + threadIdx.x;
  if (e < kE) atomicAdd(&counts[dst[e]], 1);
}

// Single-block exclusive scan of counts[16384] -> offsets, pos; also dis=rsqrt(deg).
__global__ __launch_bounds__(1024) void scan_kernel(const int* __restrict__ counts,
    int* __restrict__ offsets, int* __restrict__ pos, float* __restrict__ dis) {
  __shared__ int wave_tot[16];
  int tid = threadIdx.x;
  int base = tid * 16;
  int loc[16];
  int s = 0;
#pragma unroll
  for (int i = 0; i < 16; i++) { loc[i] = s; s += counts[base + i]; }
  int lane = tid & 63, wv = tid >> 6;
  int incl = s;
#pragma unroll
  for (int d = 1; d < 64; d <<= 1) {
    int v = __shfl_up(incl, d, 64);
    if (lane >= d) incl += v;
  }
  if (lane == 63) wave_tot[wv] = incl;
  __syncthreads();
  int woff = 0;
  for (int i = 0; i < wv; i++) woff += wave_tot[i];
  int excl = woff + incl - s;
#pragma unroll
  for (int i = 0; i < 16; i++) {
    int o = excl + loc[i];
    offsets[base + i] = o;
    pos[base + i] = o;
    dis[base + i] = rsqrtf((float)counts[base + i] + 1.0f);  // +1 self-loop
  }
}

__global__ void fill_kernel(const int* __restrict__ src, const int* __restrict__ dst,
                            int* __restrict__ pos, int* __restrict__ csr_src) {
  int e = blockIdx.x * 256 + threadIdx.x;
  if (e < kE) {
    int d = dst[e];
    int p = atomicAdd(&pos[d], 1);
    csr_src[p] = src[e];
  }
}

// ---------------------------------------------------------------- fp32 GEMM
// out[row][c] = dis[row] * sum_k a(row,k) * W[k][c]   (K fixed at 128)
// AFFINE: a = relu(A*scale + shift) applied on stage (fused BN+relu).
template <int BC, bool AFFINE>
__global__ __launch_bounds__(256) void gemm_kernel(
    const float* __restrict__ A, const float* __restrict__ W,
    const float* __restrict__ scl, const float* __restrict__ shf,
    const float* __restrict__ dis, float* __restrict__ out) {
  constexpr int NJ = BC / 16;              // cols per thread (stride 16)
  constexpr int WF4 = (32 * BC) / 4 / 256; // float4 stages of W per thread
  __shared__ float xs[64 * 33];            // 64 rows x 32 k, pad->33
  __shared__ float wsh[32 * BC];
  int tid = threadIdx.x;
  int tx = tid & 15, ty = tid >> 4;
  int r0 = blockIdx.x * 64;
  float acc[4][NJ];
#pragma unroll
  for (int r = 0; r < 4; r++)
#pragma unroll
    for (int j = 0; j < NJ; j++) acc[r][j] = 0.f;

  for (int kb = 0; kb < 128; kb += 32) {
    __syncthreads();
#pragma unroll
    for (int q = 0; q < 2; q++) {
      int f = tid + q * 256;
      int row = f >> 3, kq = f & 7;
      float4 v = *(const float4*)(A + (size_t)(r0 + row) * 128 + kb + kq * 4);
      if (AFFINE) {
        float4 s4 = *(const float4*)(scl + kb + kq * 4);
        float4 h4 = *(const float4*)(shf + kb + kq * 4);
        v.x = fmaxf(0.f, fmaf(v.x, s4.x, h4.x));
        v.y = fmaxf(0.f, fmaf(v.y, s4.y, h4.y));
        v.z = fmaxf(0.f, fmaf(v.z, s4.z, h4.z));
        v.w = fmaxf(0.f, fmaf(v.w, s4.w, h4.w));
      }
      int bb = row * 33 + kq * 4;
      xs[bb + 0] = v.x; xs[bb + 1] = v.y; xs[bb + 2] = v.z; xs[bb + 3] = v.w;
    }
#pragma unroll
    for (int q = 0; q < WF4; q++) {
      int f = tid + q * 256;
      int k = f / (BC / 4), cq = f % (BC / 4);
      *(float4*)&wsh[k * BC + cq * 4] =
          *(const float4*)(W + (size_t)(kb + k) * BC + cq * 4);
    }
    __syncthreads();
#pragma unroll
    for (int kk = 0; kk < 32; kk++) {
      float av[4];
#pragma unroll
      for (int r = 0; r < 4; r++) av[r] = xs[(ty * 4 + r) * 33 + kk];
#pragma unroll
      for (int j = 0; j < NJ; j++) {
        float bv = wsh[kk * BC + tx + j * 16];
#pragma unroll
        for (int r = 0; r < 4; r++) acc[r][j] = fmaf(av[r], bv, acc[r][j]);
      }
    }
  }
#pragma unroll
  for (int r = 0; r < 4; r++) {
    int row = r0 + ty * 4 + r;
    float dr = dis[row];
#pragma unroll
    for (int j = 0; j < NJ; j++)
      out[(size_t)row * BC + tx + j * 16] = acc[r][j] * dr;
  }
}

// ---------------------------------------------------------------- aggregation
// t[d][c] = dis[d] * (hs[d][c] + sum_{incoming edges} hs[src][c])
// unroll-4 for memory-level parallelism (index + row loads in flight).
template <int C>
__global__ void agg_kernel(const float* __restrict__ hs, const int* __restrict__ csr_src,
                           const int* __restrict__ offsets, const int* __restrict__ counts,
                           const float* __restrict__ dis, float* __restrict__ t) {
  int d = blockIdx.x;
  int c = threadIdx.x;
  float acc = hs[(size_t)d * C + c];  // self-loop
  int s0 = offsets[d];
  int n = counts[d];
  int i = 0;
  for (; i + 4 <= n; i += 4) {
    int sa = csr_src[s0 + i];
    int sb = csr_src[s0 + i + 1];
    int sc = csr_src[s0 + i + 2];
    int sd = csr_src[s0 + i + 3];
    float va = hs[(size_t)sa * C + c];
    float vb = hs[(size_t)sb * C + c];
    float vc = hs[(size_t)sc * C + c];
    float vd = hs[(size_t)sd * C + c];
    acc += va; acc += vb; acc += vc; acc += vd;
  }
  for (; i < n; i++) acc += hs[(size_t)csr_src[s0 + i] * C + c];
  t[(size_t)d * C + c] = acc * dis[d];
}

// ---------------------------------------------------------------- BN
template <int C>
__global__ __launch_bounds__(256) void stats_kernel(const float* __restrict__ t,
                                                    float* __restrict__ sums) {
  constexpr int RP = 256 / C;
  int c = threadIdx.x % C;
  int rr = threadIdx.x / C;
  float s = 0.f, s2 = 0.f;
  for (int r = blockIdx.x * RP + rr; r < kN; r += gridDim.x * RP) {
    float v = t[(size_t)r * C + c];
    s += v;
    s2 += v * v;
  }
  atomicAdd(&sums[c], s);
  atomicAdd(&sums[C + c], s2);
}

template <int C>
__global__ void finalize_kernel(const float* __restrict__ sums, const float* __restrict__ g,
                                const float* __restrict__ b, float* __restrict__ scale,
                                float* __restrict__ shift) {
  int c = threadIdx.x;
  float mean = sums[c] / (float)kN;
  float var = sums[C + c] / (float)kN - mean * mean;
  float inv = rsqrtf(var + kEps);
  float sc = g[c] * inv;
  scale[c] = sc;
  shift[c] = b[c] - mean * sc;
}

// z = relu(t2*scale+shift), stored fp32 and bf16
__global__ void applyz_kernel(const float* __restrict__ t2, const float* __restrict__ scale,
                              const float* __restrict__ shift, float* __restrict__ zf,
                              __hip_bfloat16* __restrict__ zb) {
  int i = blockIdx.x * 256 + threadIdx.x;  // kN*64 total
  int c = i & 63;
  float v = fmaxf(0.f, fmaf(t2[i], scale[c], shift[c]));
  zf[i] = v;
  zb[i] = __float2bfloat16(v);
}

// ---------------------------------------------------------------- heads
// Weights read straight from global with uniform addresses -> scalar loads
// (s_load into SGPRs) -> no LDS broadcast traffic.
__global__ __launch_bounds__(256) void heads_kernel(const float* __restrict__ zf,
    const float* __restrict__ wbin, const float* __restrict__ bbin,
    const float* __restrict__ wmc, const float* __restrict__ bmc,
    const float* __restrict__ wcont, const float* __restrict__ bcont,
    float* __restrict__ out0) {
  int n = blockIdx.x * 256 + threadIdx.x;
  float zr[64];
  const float4* z4 = (const float4*)(zf + (size_t)n * 64);
#pragma unroll
  for (int q = 0; q < 16; q++) {
    float4 v = z4[q];
    zr[4 * q] = v.x; zr[4 * q + 1] = v.y; zr[4 * q + 2] = v.z; zr[4 * q + 3] = v.w;
  }
  float lb[10], lm[10], lc[10];
#pragma unroll
  for (int j = 0; j < 10; j++) { lb[j] = bbin[j]; lm[j] = bmc[j]; lc[j] = bcont[j]; }
#pragma unroll
  for (int k = 0; k < 64; k++) {
    float v = zr[k];
#pragma unroll
    for (int j = 0; j < 10; j++) {
      lb[j] = fmaf(v, wbin[k * 10 + j], lb[j]);
      lm[j] = fmaf(v, wmc[k * 10 + j], lm[j]);
      lc[j] = fmaf(v, wcont[k * 10 + j], lc[j]);
    }
  }
  float* o = out0 + (size_t)n * 30;
#pragma unroll
  for (int j = 0; j < 10; j++) o[j] = 1.f / (1.f + expf(-lb[j]));
  float m1 = fmaxf(fmaxf(lm[0], lm[1]), fmaxf(lm[2], lm[3]));
  float e1[4], s1 = 0.f;
#pragma unroll
  for (int j = 0; j < 4; j++) { e1[j] = expf(lm[j] - m1); s1 += e1[j]; }
#pragma unroll
  for (int j = 0; j < 4; j++) o[10 + j] = e1[j] / s1;
  float m2 = lm[4];
#pragma unroll
  for (int j = 5; j < 10; j++) m2 = fmaxf(m2, lm[j]);
  float e2[6], s2 = 0.f;
#pragma unroll
  for (int j = 0; j < 6; j++) { e2[j] = expf(lm[4 + j] - m2); s2 += e2[j]; }
#pragma unroll
  for (int j = 0; j < 6; j++) o[14 + j] = e2[j] / s2;
#pragma unroll
  for (int j = 0; j < 10; j++) o[20 + j] = lc[j];
}

// ---------------------------------------------------------------- adj = z z^T (bf16 MFMA)
__global__ __launch_bounds__(256) void adj_kernel(const short* __restrict__ zb,
                                                  float* __restrict__ adj) {
  int tid = threadIdx.x;
  int wid = tid >> 6, lane = tid & 63;
  int i0 = blockIdx.x * 128 + (wid >> 1) * 64;
  int j0 = blockIdx.y * 128 + (wid & 1) * 64;
  int lr = lane & 15, lg = lane >> 4;
  short8v a[4][2], b[4][2];
#pragma unroll
  for (int mt = 0; mt < 4; mt++)
#pragma unroll
    for (int ks = 0; ks < 2; ks++)
      a[mt][ks] = *(const short8v*)(zb + (size_t)(i0 + mt * 16 + lr) * 64 + ks * 32 + lg * 8);
#pragma unroll
  for (int nt = 0; nt < 4; nt++)
#pragma unroll
    for (int ks = 0; ks < 2; ks++)
      b[nt][ks] = *(const short8v*)(zb + (size_t)(j0 + nt * 16 + lr) * 64 + ks * 32 + lg * 8);
  f32x4 acc[4][4];
#pragma unroll
  for (int mt = 0; mt < 4; mt++)
#pragma unroll
    for (int nt = 0; nt < 4; nt++) {
      f32x4 zz = {0.f, 0.f, 0.f, 0.f};
      acc[mt][nt] = zz;
    }
#pragma unroll
  for (int ks = 0; ks < 2; ks++)
#pragma unroll
    for (int mt = 0; mt < 4; mt++)
#pragma unroll
      for (int nt = 0; nt < 4; nt++)
        acc[mt][nt] = __builtin_amdgcn_mfma_f32_16x16x32_bf16(a[mt][ks], b[nt][ks],
                                                              acc[mt][nt], 0, 0, 0);
#pragma unroll
  for (int mt = 0; mt < 4; mt++)
#pragma unroll
    for (int nt = 0; nt < 4; nt++)
#pragma unroll
      for (int r = 0; r < 4; r++)
        __builtin_nontemporal_store(acc[mt][nt][r],
            &adj[(size_t)(i0 + mt * 16 + lg * 4 + r) * kN + (j0 + nt * 16 + lr)]);
}

// ---------------------------------------------------------------- edge features
// Weights from global (uniform -> s_load); z gathered as bf16 (halves traffic).
__global__ __launch_bounds__(256) void edge_kernel(const short* __restrict__ zb,
    const int* __restrict__ srcs, const int* __restrict__ dsts,
    const float* __restrict__ we, const float* __restrict__ be,
    float* __restrict__ eout) {
  int e = blockIdx.x * 256 + threadIdx.x;  // kE divisible by 256
  int s = srcs[e], d = dsts[e];
  float acc[16];
#pragma unroll
  for (int f = 0; f < 16; f++) acc[f] = be[f];
  const short8v* zs = (const short8v*)(zb + (size_t)s * 64);
#pragma unroll
  for (int q = 0; q < 8; q++) {
    short8v v = zs[q];
#pragma unroll
    for (int t = 0; t < 8; t++) {
      float vt = bf2f(v[t]);
      const float* wk = we + (q * 8 + t) * 16;
#pragma unroll
      for (int f = 0; f < 16; f++) acc[f] = fmaf(vt, wk[f], acc[f]);
    }
  }
  const short8v* zd = (const short8v*)(zb + (size_t)d * 64);
#pragma unroll
  for (int q = 0; q < 8; q++) {
    short8v v = zd[q];
#pragma unroll
    for (int t = 0; t < 8; t++) {
      float vt = bf2f(v[t]);
      const float* wk = we + (64 + q * 8 + t) * 16;
#pragma unroll
      for (int f = 0; f < 16; f++) acc[f] = fmaf(vt, wk[f], acc[f]);
    }
  }
  f32x4* o4 = (f32x4*)(eout + (size_t)e * 16);
#pragma unroll
  for (int g = 0; g < 4; g++) {
    f32x4 ov = {acc[4 * g], acc[4 * g + 1], acc[4 * g + 2], acc[4 * g + 3]};
    __builtin_nontemporal_store(ov, &o4[g]);
  }
}

// ---------------------------------------------------------------- launch
extern "C" void kernel_launch(void* const* d_in, const int* in_sizes, int n_in,
                              void* d_out, int out_size, void* d_ws, size_t ws_size,
                              hipStream_t stream) {
  const float* x      = (const float*)d_in[0];
  const int*   ei     = (const int*)d_in[1];
  const float* w1     = (const float*)d_in[3];
  const float* bn1_g  = (const float*)d_in[5];
  const float* bn1_b  = (const float*)d_in[6];
  const float* w2     = (const float*)d_in[7];
  const float* bn2_g  = (const float*)d_in[9];
  const float* bn2_b  = (const float*)d_in[10];
  const float* w_bin  = (const float*)d_in[11];
  const float* b_bin  = (const float*)d_in[12];
  const float* w_mc   = (const float*)d_in[13];
  const float* b_mc   = (const float*)d_in[14];
  const float* w_cont = (const float*)d_in[15];
  const float* b_cont = (const float*)d_in[16];
  const float* w_edge = (const float*)d_in[17];
  const float* b_edge = (const float*)d_in[18];

  float* out0 = (float*)d_out;
  float* adj  = out0 + (size_t)kN * 30;
  float* eout = adj + (size_t)kN * kN;

  char* wp = (char*)d_ws;
  auto alloc = [&](size_t bytes) {
    char* p = wp;
    wp += (bytes + 255) & ~(size_t)255;
    return p;
  };
  int*   counts  = (int*)alloc((size_t)kN * 4);
  int*   offsets = (int*)alloc((size_t)kN * 4);
  int*   pos     = (int*)alloc((size_t)kN * 4);
  int*   csr_src = (int*)alloc((size_t)kE * 4);
  float* dis     = (float*)alloc((size_t)kN * 4);
  float* sums1   = (float*)alloc(256 * 4);
  float* sums2   = (float*)alloc(128 * 4);
  float* scale1  = (float*)alloc(128 * 4);
  float* shift1  = (float*)alloc(128 * 4);
  float* scale2  = (float*)alloc(64 * 4);
  float* shift2  = (float*)alloc(64 * 4);
  float* hs1     = (float*)alloc((size_t)kN * 128 * 4);
  float* t1      = (float*)alloc((size_t)kN * 128 * 4);
  float* hs2     = (float*)alloc((size_t)kN * 64 * 4);
  float* t2      = (float*)alloc((size_t)kN * 64 * 4);
  float* zf      = (float*)alloc((size_t)kN * 64 * 4);
  __hip_bfloat16* zb = (__hip_bfloat16*)alloc((size_t)kN * 64 * 2);

  const int* esrc = ei;
  const int* edst = ei + kE;

  zero_kernel<<<dim3(64), dim3(256), 0, stream>>>(counts, sums1, sums2);
  hist_kernel<<<dim3(2048), dim3(256), 0, stream>>>(edst, counts);
  scan_kernel<<<dim3(1), dim3(1024), 0, stream>>>(counts, offsets, pos, dis);
  fill_kernel<<<dim3(2048), dim3(256), 0, stream>>>(esrc, edst, pos, csr_src);

  gemm_kernel<128, false><<<dim3(kN / 64), dim3(256), 0, stream>>>(
      x, w1, nullptr, nullptr, dis, hs1);
  agg_kernel<128><<<dim3(kN), dim3(128), 0, stream>>>(hs1, csr_src, offsets, counts, dis, t1);
  stats_kernel<128><<<dim3(64), dim3(256), 0, stream>>>(t1, sums1);
  finalize_kernel<128><<<dim3(1), dim3(128), 0, stream>>>(sums1, bn1_g, bn1_b, scale1, shift1);

  gemm_kernel<64, true><<<dim3(kN / 64), dim3(256), 0, stream>>>(
      t1, w2, scale1, shift1, dis, hs2);
  agg_kernel<64><<<dim3(kN), dim3(64), 0, stream>>>(hs2, csr_src, offsets, counts, dis, t2);
  stats_kernel<64><<<dim3(64), dim3(256), 0, stream>>>(t2, sums2);
  finalize_kernel<64><<<dim3(1), dim3(64), 0, stream>>>(sums2, bn2_g, bn2_b, scale2, shift2);

  applyz_kernel<<<dim3(kN * 64 / 256), dim3(256), 0, stream>>>(t2, scale2, shift2, zf, zb);

  heads_kernel<<<dim3(kN / 256), dim3(256), 0, stream>>>(
      zf, w_bin, b_bin, w_mc, b_mc, w_cont, b_cont, out0);
  adj_kernel<<<dim3(kN / 128, kN / 128), dim3(256), 0, stream>>>((const short*)zb, adj);
  edge_kernel<<<dim3(kE / 256), dim3(256), 0, stream>>>((const short*)zb, esrc, edst,
                                                        w_edge, b_edge, eout);
}

// Round 3
// 499.013 us; speedup vs baseline: 1.2820x; 1.2820x over previous
//
#include <hip/hip_runtime.h>
#include <hip/hip_bf16.h>
#include <math.h>

// GAE on MI355X. N=16384 nodes, E=524288 edges.
// R3: R1 structure (LDS-broadcast weights, plain cached stores) + bf16 z
// gathers in edge kernel + unroll-4 aggregation loop.

constexpr int kN = 16384;
constexpr int kE = 524288;
constexpr float kEps = 1e-5f;

typedef __attribute__((ext_vector_type(8))) short short8v;   // 8 x bf16
typedef __attribute__((ext_vector_type(4))) float f32x4;

__device__ inline float bf2f(short u) {
  return __uint_as_float(((unsigned)(unsigned short)u) << 16);
}

// ---------------------------------------------------------------- utility
__global__ void zero_kernel(int* counts, float* sums1, float* sums2) {
  int i = blockIdx.x * 256 + threadIdx.x;
  if (i < kN) counts[i] = 0;
  if (i < 256) sums1[i] = 0.f;
  if (i < 128) sums2[i] = 0.f;
}

__global__ void hist_kernel(const int* __restrict__ dst, int* __restrict__ counts) {
  int e = blockIdx.x * 256 + threadIdx.x;
  if (e < kE) atomicAdd(&counts[dst[e]], 1);
}

// Single-block exclusive scan of counts[16384] -> offsets, pos; also dis=rsqrt(deg).
__global__ __launch_bounds__(1024) void scan_kernel(const int* __restrict__ counts,
    int* __restrict__ offsets, int* __restrict__ pos, float* __restrict__ dis) {
  __shared__ int wave_tot[16];
  int tid = threadIdx.x;
  int base = tid * 16;
  int loc[16];
  int s = 0;
#pragma unroll
  for (int i = 0; i < 16; i++) { loc[i] = s; s += counts[base + i]; }
  int lane = tid & 63, wv = tid >> 6;
  int incl = s;
#pragma unroll
  for (int d = 1; d < 64; d <<= 1) {
    int v = __shfl_up(incl, d, 64);
    if (lane >= d) incl += v;
  }
  if (lane == 63) wave_tot[wv] = incl;
  __syncthreads();
  int woff = 0;
  for (int i = 0; i < wv; i++) woff += wave_tot[i];
  int excl = woff + incl - s;
#pragma unroll
  for (int i = 0; i < 16; i++) {
    int o = excl + loc[i];
    offsets[base + i] = o;
    pos[base + i] = o;
    dis[base + i] = rsqrtf((float)counts[base + i] + 1.0f);  // +1 self-loop
  }
}

__global__ void fill_kernel(const int* __restrict__ src, const int* __restrict__ dst,
                            int* __restrict__ pos, int* __restrict__ csr_src) {
  int e = blockIdx.x * 256 + threadIdx.x;
  if (e < kE) {
    int d = dst[e];
    int p = atomicAdd(&pos[d], 1);
    csr_src[p] = src[e];
  }
}

// ---------------------------------------------------------------- fp32 GEMM
// out[row][c] = dis[row] * sum_k a(row,k) * W[k][c]   (K fixed at 128)
// AFFINE: a = relu(A*scale + shift) applied on stage (fused BN+relu).
template <int BC, bool AFFINE>
__global__ __launch_bounds__(256) void gemm_kernel(
    const float* __restrict__ A, const float* __restrict__ W,
    const float* __restrict__ scl, const float* __restrict__ shf,
    const float* __restrict__ dis, float* __restrict__ out) {
  constexpr int NJ = BC / 16;              // cols per thread (stride 16)
  constexpr int WF4 = (32 * BC) / 4 / 256; // float4 stages of W per thread
  __shared__ float xs[64 * 33];            // 64 rows x 32 k, pad->33
  __shared__ float wsh[32 * BC];
  int tid = threadIdx.x;
  int tx = tid & 15, ty = tid >> 4;
  int r0 = blockIdx.x * 64;
  float acc[4][NJ];
#pragma unroll
  for (int r = 0; r < 4; r++)
#pragma unroll
    for (int j = 0; j < NJ; j++) acc[r][j] = 0.f;

  for (int kb = 0; kb < 128; kb += 32) {
    __syncthreads();
#pragma unroll
    for (int q = 0; q < 2; q++) {
      int f = tid + q * 256;
      int row = f >> 3, kq = f & 7;
      float4 v = *(const float4*)(A + (size_t)(r0 + row) * 128 + kb + kq * 4);
      if (AFFINE) {
        float4 s4 = *(const float4*)(scl + kb + kq * 4);
        float4 h4 = *(const float4*)(shf + kb + kq * 4);
        v.x = fmaxf(0.f, fmaf(v.x, s4.x, h4.x));
        v.y = fmaxf(0.f, fmaf(v.y, s4.y, h4.y));
        v.z = fmaxf(0.f, fmaf(v.z, s4.z, h4.z));
        v.w = fmaxf(0.f, fmaf(v.w, s4.w, h4.w));
      }
      int bb = row * 33 + kq * 4;
      xs[bb + 0] = v.x; xs[bb + 1] = v.y; xs[bb + 2] = v.z; xs[bb + 3] = v.w;
    }
#pragma unroll
    for (int q = 0; q < WF4; q++) {
      int f = tid + q * 256;
      int k = f / (BC / 4), cq = f % (BC / 4);
      *(float4*)&wsh[k * BC + cq * 4] =
          *(const float4*)(W + (size_t)(kb + k) * BC + cq * 4);
    }
    __syncthreads();
#pragma unroll
    for (int kk = 0; kk < 32; kk++) {
      float av[4];
#pragma unroll
      for (int r = 0; r < 4; r++) av[r] = xs[(ty * 4 + r) * 33 + kk];
#pragma unroll
      for (int j = 0; j < NJ; j++) {
        float bv = wsh[kk * BC + tx + j * 16];
#pragma unroll
        for (int r = 0; r < 4; r++) acc[r][j] = fmaf(av[r], bv, acc[r][j]);
      }
    }
  }
#pragma unroll
  for (int r = 0; r < 4; r++) {
    int row = r0 + ty * 4 + r;
    float dr = dis[row];
#pragma unroll
    for (int j = 0; j < NJ; j++)
      out[(size_t)row * BC + tx + j * 16] = acc[r][j] * dr;
  }
}

// ---------------------------------------------------------------- aggregation
// t[d][c] = dis[d] * (hs[d][c] + sum_{incoming edges} hs[src][c])
template <int C>
__global__ void agg_kernel(const float* __restrict__ hs, const int* __restrict__ csr_src,
                           const int* __restrict__ offsets, const int* __restrict__ counts,
                           const float* __restrict__ dis, float* __restrict__ t) {
  int d = blockIdx.x;
  int c = threadIdx.x;
  float acc = hs[(size_t)d * C + c];  // self-loop
  int s0 = offsets[d];
  int n = counts[d];
  int i = 0;
  for (; i + 4 <= n; i += 4) {
    int sa = csr_src[s0 + i];
    int sb = csr_src[s0 + i + 1];
    int sc = csr_src[s0 + i + 2];
    int sd = csr_src[s0 + i + 3];
    float va = hs[(size_t)sa * C + c];
    float vb = hs[(size_t)sb * C + c];
    float vc = hs[(size_t)sc * C + c];
    float vd = hs[(size_t)sd * C + c];
    acc += va; acc += vb; acc += vc; acc += vd;
  }
  for (; i < n; i++) acc += hs[(size_t)csr_src[s0 + i] * C + c];
  t[(size_t)d * C + c] = acc * dis[d];
}

// ---------------------------------------------------------------- BN
template <int C>
__global__ __launch_bounds__(256) void stats_kernel(const float* __restrict__ t,
                                                    float* __restrict__ sums) {
  constexpr int RP = 256 / C;
  int c = threadIdx.x % C;
  int rr = threadIdx.x / C;
  float s = 0.f, s2 = 0.f;
  for (int r = blockIdx.x * RP + rr; r < kN; r += gridDim.x * RP) {
    float v = t[(size_t)r * C + c];
    s += v;
    s2 += v * v;
  }
  atomicAdd(&sums[c], s);
  atomicAdd(&sums[C + c], s2);
}

template <int C>
__global__ void finalize_kernel(const float* __restrict__ sums, const float* __restrict__ g,
                                const float* __restrict__ b, float* __restrict__ scale,
                                float* __restrict__ shift) {
  int c = threadIdx.x;
  float mean = sums[c] / (float)kN;
  float var = sums[C + c] / (float)kN - mean * mean;
  float inv = rsqrtf(var + kEps);
  float sc = g[c] * inv;
  scale[c] = sc;
  shift[c] = b[c] - mean * sc;
}

// z = relu(t2*scale+shift), stored fp32 and bf16
__global__ void applyz_kernel(const float* __restrict__ t2, const float* __restrict__ scale,
                              const float* __restrict__ shift, float* __restrict__ zf,
                              __hip_bfloat16* __restrict__ zb) {
  int i = blockIdx.x * 256 + threadIdx.x;  // kN*64 total
  int c = i & 63;
  float v = fmaxf(0.f, fmaf(t2[i], scale[c], shift[c]));
  zf[i] = v;
  zb[i] = __float2bfloat16(v);
}

// ---------------------------------------------------------------- heads
__global__ __launch_bounds__(256) void heads_kernel(const float* __restrict__ zf,
    const float* __restrict__ wbin, const float* __restrict__ bbin,
    const float* __restrict__ wmc, const float* __restrict__ bmc,
    const float* __restrict__ wcont, const float* __restrict__ bcont,
    float* __restrict__ out0) {
  __shared__ float wB[640], wM[640], wC[640], bB[16], bM[16], bC[16];
  int tid = threadIdx.x;
  for (int i = tid; i < 640; i += 256) { wB[i] = wbin[i]; wM[i] = wmc[i]; wC[i] = wcont[i]; }
  if (tid < 10) { bB[tid] = bbin[tid]; bM[tid] = bmc[tid]; bC[tid] = bcont[tid]; }
  __syncthreads();
  int n = blockIdx.x * 256 + tid;
  float zr[64];
  const float4* z4 = (const float4*)(zf + (size_t)n * 64);
#pragma unroll
  for (int q = 0; q < 16; q++) {
    float4 v = z4[q];
    zr[4 * q] = v.x; zr[4 * q + 1] = v.y; zr[4 * q + 2] = v.z; zr[4 * q + 3] = v.w;
  }
  float lb[10], lm[10], lc[10];
#pragma unroll
  for (int j = 0; j < 10; j++) { lb[j] = bB[j]; lm[j] = bM[j]; lc[j] = bC[j]; }
#pragma unroll
  for (int k = 0; k < 64; k++) {
    float v = zr[k];
#pragma unroll
    for (int j = 0; j < 10; j++) {
      lb[j] = fmaf(v, wB[k * 10 + j], lb[j]);
      lm[j] = fmaf(v, wM[k * 10 + j], lm[j]);
      lc[j] = fmaf(v, wC[k * 10 + j], lc[j]);
    }
  }
  float* o = out0 + (size_t)n * 30;
#pragma unroll
  for (int j = 0; j < 10; j++) o[j] = 1.f / (1.f + expf(-lb[j]));
  float m1 = fmaxf(fmaxf(lm[0], lm[1]), fmaxf(lm[2], lm[3]));
  float e1[4], s1 = 0.f;
#pragma unroll
  for (int j = 0; j < 4; j++) { e1[j] = expf(lm[j] - m1); s1 += e1[j]; }
#pragma unroll
  for (int j = 0; j < 4; j++) o[10 + j] = e1[j] / s1;
  float m2 = lm[4];
#pragma unroll
  for (int j = 5; j < 10; j++) m2 = fmaxf(m2, lm[j]);
  float e2[6], s2 = 0.f;
#pragma unroll
  for (int j = 0; j < 6; j++) { e2[j] = expf(lm[4 + j] - m2); s2 += e2[j]; }
#pragma unroll
  for (int j = 0; j < 6; j++) o[14 + j] = e2[j] / s2;
#pragma unroll
  for (int j = 0; j < 10; j++) o[20 + j] = lc[j];
}

// ---------------------------------------------------------------- adj = z z^T (bf16 MFMA)
// Block: 256 thr = 4 waves, tile 128x128; wave tile 64x64 = 4x4 frags of 16x16, K=64.
__global__ __launch_bounds__(256) void adj_kernel(const short* __restrict__ zb,
                                                  float* __restrict__ adj) {
  int tid = threadIdx.x;
  int wid = tid >> 6, lane = tid & 63;
  int i0 = blockIdx.x * 128 + (wid >> 1) * 64;
  int j0 = blockIdx.y * 128 + (wid & 1) * 64;
  int lr = lane & 15, lg = lane >> 4;
  short8v a[4][2], b[4][2];
#pragma unroll
  for (int mt = 0; mt < 4; mt++)
#pragma unroll
    for (int ks = 0; ks < 2; ks++)
      a[mt][ks] = *(const short8v*)(zb + (size_t)(i0 + mt * 16 + lr) * 64 + ks * 32 + lg * 8);
#pragma unroll
  for (int nt = 0; nt < 4; nt++)
#pragma unroll
    for (int ks = 0; ks < 2; ks++)
      b[nt][ks] = *(const short8v*)(zb + (size_t)(j0 + nt * 16 + lr) * 64 + ks * 32 + lg * 8);
  f32x4 acc[4][4];
#pragma unroll
  for (int mt = 0; mt < 4; mt++)
#pragma unroll
    for (int nt = 0; nt < 4; nt++) {
      f32x4 zz = {0.f, 0.f, 0.f, 0.f};
      acc[mt][nt] = zz;
    }
#pragma unroll
  for (int ks = 0; ks < 2; ks++)
#pragma unroll
    for (int mt = 0; mt < 4; mt++)
#pragma unroll
      for (int nt = 0; nt < 4; nt++)
        acc[mt][nt] = __builtin_amdgcn_mfma_f32_16x16x32_bf16(a[mt][ks], b[nt][ks],
                                                              acc[mt][nt], 0, 0, 0);
#pragma unroll
  for (int mt = 0; mt < 4; mt++)
#pragma unroll
    for (int nt = 0; nt < 4; nt++)
#pragma unroll
      for (int r = 0; r < 4; r++)
        adj[(size_t)(i0 + mt * 16 + lg * 4 + r) * kN + (j0 + nt * 16 + lr)] =
            acc[mt][nt][r];
}

// ---------------------------------------------------------------- edge features
// Weights staged in LDS (reads are same-address broadcasts: conflict-free);
// z gathered as bf16 (halves gather traffic vs fp32).
__global__ __launch_bounds__(256) void edge_kernel(const short* __restrict__ zb,
    const int* __restrict__ srcs, const int* __restrict__ dsts,
    const float* __restrict__ we, const float* __restrict__ be,
    float* __restrict__ eout) {
  __shared__ float w[2048];  // 128 x 16
  __shared__ float bb[16];
  int tid = threadIdx.x;
  for (int i = tid; i < 2048; i += 256) w[i] = we[i];
  if (tid < 16) bb[tid] = be[tid];
  __syncthreads();
  int e = blockIdx.x * 256 + tid;  // kE divisible by 256
  int s = srcs[e], d = dsts[e];
  float acc[16];
#pragma unroll
  for (int f = 0; f < 16; f++) acc[f] = bb[f];
  const short8v* zs = (const short8v*)(zb + (size_t)s * 64);
#pragma unroll
  for (int q = 0; q < 8; q++) {
    short8v v = zs[q];
#pragma unroll
    for (int t = 0; t < 8; t++) {
      float vt = bf2f(v[t]);
      const float* wk = &w[(q * 8 + t) * 16];
#pragma unroll
      for (int f = 0; f < 16; f++) acc[f] = fmaf(vt, wk[f], acc[f]);
    }
  }
  const short8v* zd = (const short8v*)(zb + (size_t)d * 64);
#pragma unroll
  for (int q = 0; q < 8; q++) {
    short8v v = zd[q];
#pragma unroll
    for (int t = 0; t < 8; t++) {
      float vt = bf2f(v[t]);
      const float* wk = &w[1024 + (q * 8 + t) * 16];
#pragma unroll
      for (int f = 0; f < 16; f++) acc[f] = fmaf(vt, wk[f], acc[f]);
    }
  }
  float4* o4 = (float4*)(eout + (size_t)e * 16);
  o4[0] = make_float4(acc[0], acc[1], acc[2], acc[3]);
  o4[1] = make_float4(acc[4], acc[5], acc[6], acc[7]);
  o4[2] = make_float4(acc[8], acc[9], acc[10], acc[11]);
  o4[3] = make_float4(acc[12], acc[13], acc[14], acc[15]);
}

// ---------------------------------------------------------------- launch
extern "C" void kernel_launch(void* const* d_in, const int* in_sizes, int n_in,
                              void* d_out, int out_size, void* d_ws, size_t ws_size,
                              hipStream_t stream) {
  const float* x      = (const float*)d_in[0];
  const int*   ei     = (const int*)d_in[1];
  const float* w1     = (const float*)d_in[3];
  const float* bn1_g  = (const float*)d_in[5];
  const float* bn1_b  = (const float*)d_in[6];
  const float* w2     = (const float*)d_in[7];
  const float* bn2_g  = (const float*)d_in[9];
  const float* bn2_b  = (const float*)d_in[10];
  const float* w_bin  = (const float*)d_in[11];
  const float* b_bin  = (const float*)d_in[12];
  const float* w_mc   = (const float*)d_in[13];
  const float* b_mc   = (const float*)d_in[14];
  const float* w_cont = (const float*)d_in[15];
  const float* b_cont = (const float*)d_in[16];
  const float* w_edge = (const float*)d_in[17];
  const float* b_edge = (const float*)d_in[18];

  float* out0 = (float*)d_out;
  float* adj  = out0 + (size_t)kN * 30;
  float* eout = adj + (size_t)kN * kN;

  char* wp = (char*)d_ws;
  auto alloc = [&](size_t bytes) {
    char* p = wp;
    wp += (bytes + 255) & ~(size_t)255;
    return p;
  };
  int*   counts  = (int*)alloc((size_t)kN * 4);
  int*   offsets = (int*)alloc((size_t)kN * 4);
  int*   pos     = (int*)alloc((size_t)kN * 4);
  int*   csr_src = (int*)alloc((size_t)kE * 4);
  float* dis     = (float*)alloc((size_t)kN * 4);
  float* sums1   = (float*)alloc(256 * 4);
  float* sums2   = (float*)alloc(128 * 4);
  float* scale1  = (float*)alloc(128 * 4);
  float* shift1  = (float*)alloc(128 * 4);
  float* scale2  = (float*)alloc(64 * 4);
  float* shift2  = (float*)alloc(64 * 4);
  float* hs1     = (float*)alloc((size_t)kN * 128 * 4);
  float* t1      = (float*)alloc((size_t)kN * 128 * 4);
  float* hs2     = (float*)alloc((size_t)kN * 64 * 4);
  float* t2      = (float*)alloc((size_t)kN * 64 * 4);
  float* zf      = (float*)alloc((size_t)kN * 64 * 4);
  __hip_bfloat16* zb = (__hip_bfloat16*)alloc((size_t)kN * 64 * 2);

  const int* esrc = ei;
  const int* edst = ei + kE;

  zero_kernel<<<dim3(64), dim3(256), 0, stream>>>(counts, sums1, sums2);
  hist_kernel<<<dim3(2048), dim3(256), 0, stream>>>(edst, counts);
  scan_kernel<<<dim3(1), dim3(1024), 0, stream>>>(counts, offsets, pos, dis);
  fill_kernel<<<dim3(2048), dim3(256), 0, stream>>>(esrc, edst, pos, csr_src);

  gemm_kernel<128, false><<<dim3(kN / 64), dim3(256), 0, stream>>>(
      x, w1, nullptr, nullptr, dis, hs1);
  agg_kernel<128><<<dim3(kN), dim3(128), 0, stream>>>(hs1, csr_src, offsets, counts, dis, t1);
  stats_kernel<128><<<dim3(64), dim3(256), 0, stream>>>(t1, sums1);
  finalize_kernel<128><<<dim3(1), dim3(128), 0, stream>>>(sums1, bn1_g, bn1_b, scale1, shift1);

  gemm_kernel<64, true><<<dim3(kN / 64), dim3(256), 0, stream>>>(
      t1, w2, scale1, shift1, dis, hs2);
  agg_kernel<64><<<dim3(kN), dim3(64), 0, stream>>>(hs2, csr_src, offsets, counts, dis, t2);
  stats_kernel<64><<<dim3(64), dim3(256), 0, stream>>>(t2, sums2);
  finalize_kernel<64><<<dim3(1), dim3(64), 0, stream>>>(sums2, bn2_g, bn2_b, scale2, shift2);

  applyz_kernel<<<dim3(kN * 64 / 256), dim3(256), 0, stream>>>(t2, scale2, shift2, zf, zb);

  heads_kernel<<<dim3(kN / 256), dim3(256), 0, stream>>>(
      zf, w_bin, b_bin, w_mc, b_mc, w_cont, b_cont, out0);
  adj_kernel<<<dim3(kN / 128, kN / 128), dim3(256), 0, stream>>>((const short*)zb, adj);
  edge_kernel<<<dim3(kE / 256), dim3(256), 0, stream>>>((const short*)zb, esrc, edst,
                                                        w_edge, b_edge, eout);
}

// Round 4
// 487.761 us; speedup vs baseline: 1.3116x; 1.0231x over previous
//
#include <hip/hip_runtime.h>
#include <hip/hip_bf16.h>
#include <math.h>

// GAE on MI355X. N=16384 nodes, E=524288 edges.
// R4: edge kernel processes 4 edges/thread with float4 LDS weight broadcasts
// (16x fewer LDS cycles per edge); heads kernel uses transposed LDS weights
// with float4 reads; stats grid 256. Rest identical to R3 (known good).

constexpr int kN = 16384;
constexpr int kE = 524288;
constexpr float kEps = 1e-5f;

typedef __attribute__((ext_vector_type(8))) short short8v;   // 8 x bf16
typedef __attribute__((ext_vector_type(4))) float f32x4;

__device__ inline float bf2f(short u) {
  return __uint_as_float(((unsigned)(unsigned short)u) << 16);
}

// ---------------------------------------------------------------- utility
__global__ void zero_kernel(int* counts, float* sums1, float* sums2) {
  int i = blockIdx.x * 256 + threadIdx.x;
  if (i < kN) counts[i] = 0;
  if (i < 256) sums1[i] = 0.f;
  if (i < 128) sums2[i] = 0.f;
}

__global__ void hist_kernel(const int* __restrict__ dst, int* __restrict__ counts) {
  int e = blockIdx.x * 256 + threadIdx.x;
  if (e < kE) atomicAdd(&counts[dst[e]], 1);
}

// Single-block exclusive scan of counts[16384] -> offsets, pos; also dis=rsqrt(deg).
__global__ __launch_bounds__(1024) void scan_kernel(const int* __restrict__ counts,
    int* __restrict__ offsets, int* __restrict__ pos, float* __restrict__ dis) {
  __shared__ int wave_tot[16];
  int tid = threadIdx.x;
  int base = tid * 16;
  int loc[16];
  int s = 0;
#pragma unroll
  for (int i = 0; i < 16; i++) { loc[i] = s; s += counts[base + i]; }
  int lane = tid & 63, wv = tid >> 6;
  int incl = s;
#pragma unroll
  for (int d = 1; d < 64; d <<= 1) {
    int v = __shfl_up(incl, d, 64);
    if (lane >= d) incl += v;
  }
  if (lane == 63) wave_tot[wv] = incl;
  __syncthreads();
  int woff = 0;
  for (int i = 0; i < wv; i++) woff += wave_tot[i];
  int excl = woff + incl - s;
#pragma unroll
  for (int i = 0; i < 16; i++) {
    int o = excl + loc[i];
    offsets[base + i] = o;
    pos[base + i] = o;
    dis[base + i] = rsqrtf((float)counts[base + i] + 1.0f);  // +1 self-loop
  }
}

__global__ void fill_kernel(const int* __restrict__ src, const int* __restrict__ dst,
                            int* __restrict__ pos, int* __restrict__ csr_src) {
  int e = blockIdx.x * 256 + threadIdx.x;
  if (e < kE) {
    int d = dst[e];
    int p = atomicAdd(&pos[d], 1);
    csr_src[p] = src[e];
  }
}

// ---------------------------------------------------------------- fp32 GEMM
template <int BC, bool AFFINE>
__global__ __launch_bounds__(256) void gemm_kernel(
    const float* __restrict__ A, const float* __restrict__ W,
    const float* __restrict__ scl, const float* __restrict__ shf,
    const float* __restrict__ dis, float* __restrict__ out) {
  constexpr int NJ = BC / 16;              // cols per thread (stride 16)
  constexpr int WF4 = (32 * BC) / 4 / 256; // float4 stages of W per thread
  __shared__ float xs[64 * 33];            // 64 rows x 32 k, pad->33
  __shared__ float wsh[32 * BC];
  int tid = threadIdx.x;
  int tx = tid & 15, ty = tid >> 4;
  int r0 = blockIdx.x * 64;
  float acc[4][NJ];
#pragma unroll
  for (int r = 0; r < 4; r++)
#pragma unroll
    for (int j = 0; j < NJ; j++) acc[r][j] = 0.f;

  for (int kb = 0; kb < 128; kb += 32) {
    __syncthreads();
#pragma unroll
    for (int q = 0; q < 2; q++) {
      int f = tid + q * 256;
      int row = f >> 3, kq = f & 7;
      float4 v = *(const float4*)(A + (size_t)(r0 + row) * 128 + kb + kq * 4);
      if (AFFINE) {
        float4 s4 = *(const float4*)(scl + kb + kq * 4);
        float4 h4 = *(const float4*)(shf + kb + kq * 4);
        v.x = fmaxf(0.f, fmaf(v.x, s4.x, h4.x));
        v.y = fmaxf(0.f, fmaf(v.y, s4.y, h4.y));
        v.z = fmaxf(0.f, fmaf(v.z, s4.z, h4.z));
        v.w = fmaxf(0.f, fmaf(v.w, s4.w, h4.w));
      }
      int bb = row * 33 + kq * 4;
      xs[bb + 0] = v.x; xs[bb + 1] = v.y; xs[bb + 2] = v.z; xs[bb + 3] = v.w;
    }
#pragma unroll
    for (int q = 0; q < WF4; q++) {
      int f = tid + q * 256;
      int k = f / (BC / 4), cq = f % (BC / 4);
      *(float4*)&wsh[k * BC + cq * 4] =
          *(const float4*)(W + (size_t)(kb + k) * BC + cq * 4);
    }
    __syncthreads();
#pragma unroll
    for (int kk = 0; kk < 32; kk++) {
      float av[4];
#pragma unroll
      for (int r = 0; r < 4; r++) av[r] = xs[(ty * 4 + r) * 33 + kk];
#pragma unroll
      for (int j = 0; j < NJ; j++) {
        float bv = wsh[kk * BC + tx + j * 16];
#pragma unroll
        for (int r = 0; r < 4; r++) acc[r][j] = fmaf(av[r], bv, acc[r][j]);
      }
    }
  }
#pragma unroll
  for (int r = 0; r < 4; r++) {
    int row = r0 + ty * 4 + r;
    float dr = dis[row];
#pragma unroll
    for (int j = 0; j < NJ; j++)
      out[(size_t)row * BC + tx + j * 16] = acc[r][j] * dr;
  }
}

// ---------------------------------------------------------------- aggregation
template <int C>
__global__ void agg_kernel(const float* __restrict__ hs, const int* __restrict__ csr_src,
                           const int* __restrict__ offsets, const int* __restrict__ counts,
                           const float* __restrict__ dis, float* __restrict__ t) {
  int d = blockIdx.x;
  int c = threadIdx.x;
  float acc = hs[(size_t)d * C + c];  // self-loop
  int s0 = offsets[d];
  int n = counts[d];
  int i = 0;
  for (; i + 4 <= n; i += 4) {
    int sa = csr_src[s0 + i];
    int sb = csr_src[s0 + i + 1];
    int sc = csr_src[s0 + i + 2];
    int sd = csr_src[s0 + i + 3];
    float va = hs[(size_t)sa * C + c];
    float vb = hs[(size_t)sb * C + c];
    float vc = hs[(size_t)sc * C + c];
    float vd = hs[(size_t)sd * C + c];
    acc += va; acc += vb; acc += vc; acc += vd;
  }
  for (; i < n; i++) acc += hs[(size_t)csr_src[s0 + i] * C + c];
  t[(size_t)d * C + c] = acc * dis[d];
}

// ---------------------------------------------------------------- BN
template <int C>
__global__ __launch_bounds__(256) void stats_kernel(const float* __restrict__ t,
                                                    float* __restrict__ sums) {
  constexpr int RP = 256 / C;
  int c = threadIdx.x % C;
  int rr = threadIdx.x / C;
  float s = 0.f, s2 = 0.f;
  for (int r = blockIdx.x * RP + rr; r < kN; r += gridDim.x * RP) {
    float v = t[(size_t)r * C + c];
    s += v;
    s2 += v * v;
  }
  atomicAdd(&sums[c], s);
  atomicAdd(&sums[C + c], s2);
}

template <int C>
__global__ void finalize_kernel(const float* __restrict__ sums, const float* __restrict__ g,
                                const float* __restrict__ b, float* __restrict__ scale,
                                float* __restrict__ shift) {
  int c = threadIdx.x;
  float mean = sums[c] / (float)kN;
  float var = sums[C + c] / (float)kN - mean * mean;
  float inv = rsqrtf(var + kEps);
  float sc = g[c] * inv;
  scale[c] = sc;
  shift[c] = b[c] - mean * sc;
}

// z = relu(t2*scale+shift), stored fp32 and bf16
__global__ void applyz_kernel(const float* __restrict__ t2, const float* __restrict__ scale,
                              const float* __restrict__ shift, float* __restrict__ zf,
                              __hip_bfloat16* __restrict__ zb) {
  int i = blockIdx.x * 256 + threadIdx.x;  // kN*64 total
  int c = i & 63;
  float v = fmaxf(0.f, fmaf(t2[i], scale[c], shift[c]));
  zf[i] = v;
  zb[i] = __float2bfloat16(v);
}

// ---------------------------------------------------------------- heads
// LDS weights transposed to [j][64] so the k-loop reads float4 broadcasts.
__global__ __launch_bounds__(256) void heads_kernel(const float* __restrict__ zf,
    const float* __restrict__ wbin, const float* __restrict__ bbin,
    const float* __restrict__ wmc, const float* __restrict__ bmc,
    const float* __restrict__ wcont, const float* __restrict__ bcont,
    float* __restrict__ out0) {
  __shared__ float wT[30 * 64];
  __shared__ float bias[32];
  int tid = threadIdx.x;
  for (int idx = tid; idx < 1920; idx += 256) {
    int j = idx >> 6, k = idx & 63;
    const float* src = (j < 10) ? wbin : (j < 20) ? wmc : wcont;
    wT[idx] = src[k * 10 + (j % 10)];
  }
  if (tid < 30)
    bias[tid] = (tid < 10) ? bbin[tid] : (tid < 20) ? bmc[tid - 10] : bcont[tid - 20];
  __syncthreads();
  int n = blockIdx.x * 256 + tid;
  float zr[64];
  const float4* z4 = (const float4*)(zf + (size_t)n * 64);
#pragma unroll
  for (int q = 0; q < 16; q++) {
    float4 v = z4[q];
    zr[4 * q] = v.x; zr[4 * q + 1] = v.y; zr[4 * q + 2] = v.z; zr[4 * q + 3] = v.w;
  }
  float acc[30];
#pragma unroll
  for (int j = 0; j < 30; j++) {
    float s = bias[j];
#pragma unroll
    for (int kc = 0; kc < 16; kc++) {
      f32x4 wv = *(const f32x4*)&wT[j * 64 + kc * 4];
      s = fmaf(zr[4 * kc + 0], wv.x, s);
      s = fmaf(zr[4 * kc + 1], wv.y, s);
      s = fmaf(zr[4 * kc + 2], wv.z, s);
      s = fmaf(zr[4 * kc + 3], wv.w, s);
    }
    acc[j] = s;
  }
  float* o = out0 + (size_t)n * 30;
#pragma unroll
  for (int j = 0; j < 10; j++) o[j] = 1.f / (1.f + expf(-acc[j]));
  float m1 = fmaxf(fmaxf(acc[10], acc[11]), fmaxf(acc[12], acc[13]));
  float e1[4], s1 = 0.f;
#pragma unroll
  for (int j = 0; j < 4; j++) { e1[j] = expf(acc[10 + j] - m1); s1 += e1[j]; }
#pragma unroll
  for (int j = 0; j < 4; j++) o[10 + j] = e1[j] / s1;
  float m2 = acc[14];
#pragma unroll
  for (int j = 15; j < 20; j++) m2 = fmaxf(m2, acc[j]);
  float e2[6], s2 = 0.f;
#pragma unroll
  for (int j = 0; j < 6; j++) { e2[j] = expf(acc[14 + j] - m2); s2 += e2[j]; }
#pragma unroll
  for (int j = 0; j < 6; j++) o[14 + j] = e2[j] / s2;
#pragma unroll
  for (int j = 0; j < 10; j++) o[20 + j] = acc[20 + j];
}

// ---------------------------------------------------------------- adj = z z^T (bf16 MFMA)
__global__ __launch_bounds__(256) void adj_kernel(const short* __restrict__ zb,
                                                  float* __restrict__ adj) {
  int tid = threadIdx.x;
  int wid = tid >> 6, lane = tid & 63;
  int i0 = blockIdx.x * 128 + (wid >> 1) * 64;
  int j0 = blockIdx.y * 128 + (wid & 1) * 64;
  int lr = lane & 15, lg = lane >> 4;
  short8v a[4][2], b[4][2];
#pragma unroll
  for (int mt = 0; mt < 4; mt++)
#pragma unroll
    for (int ks = 0; ks < 2; ks++)
      a[mt][ks] = *(const short8v*)(zb + (size_t)(i0 + mt * 16 + lr) * 64 + ks * 32 + lg * 8);
#pragma unroll
  for (int nt = 0; nt < 4; nt++)
#pragma unroll
    for (int ks = 0; ks < 2; ks++)
      b[nt][ks] = *(const short8v*)(zb + (size_t)(j0 + nt * 16 + lr) * 64 + ks * 32 + lg * 8);
  f32x4 acc[4][4];
#pragma unroll
  for (int mt = 0; mt < 4; mt++)
#pragma unroll
    for (int nt = 0; nt < 4; nt++) {
      f32x4 zz = {0.f, 0.f, 0.f, 0.f};
      acc[mt][nt] = zz;
    }
#pragma unroll
  for (int ks = 0; ks < 2; ks++)
#pragma unroll
    for (int mt = 0; mt < 4; mt++)
#pragma unroll
      for (int nt = 0; nt < 4; nt++)
        acc[mt][nt] = __builtin_amdgcn_mfma_f32_16x16x32_bf16(a[mt][ks], b[nt][ks],
                                                              acc[mt][nt], 0, 0, 0);
#pragma unroll
  for (int mt = 0; mt < 4; mt++)
#pragma unroll
    for (int nt = 0; nt < 4; nt++)
#pragma unroll
      for (int r = 0; r < 4; r++)
        adj[(size_t)(i0 + mt * 16 + lg * 4 + r) * kN + (j0 + nt * 16 + lr)] =
            acc[mt][nt][r];
}

// ---------------------------------------------------------------- edge features
// 4 edges per thread: LDS float4 weight broadcasts amortized 4x; bf16 z gathers.
__global__ __launch_bounds__(256) void edge_kernel(const short* __restrict__ zb,
    const int* __restrict__ srcs, const int* __restrict__ dsts,
    const float* __restrict__ we, const float* __restrict__ be,
    float* __restrict__ eout) {
  __shared__ float w[2048];  // 128 x 16
  __shared__ float bb[16];
  int tid = threadIdx.x;
  for (int i = tid; i < 2048; i += 256) w[i] = we[i];
  if (tid < 16) bb[tid] = be[tid];
  __syncthreads();
  int base = blockIdx.x * 1024 + tid;  // 1024 edges per block, kE/1024 = 512 blocks
  int s[4], d[4];
#pragma unroll
  for (int i = 0; i < 4; i++) { s[i] = srcs[base + i * 256]; d[i] = dsts[base + i * 256]; }
  float acc[4][16];
#pragma unroll
  for (int i = 0; i < 4; i++)
#pragma unroll
    for (int f = 0; f < 16; f++) acc[i][f] = bb[f];

#pragma unroll 2
  for (int q = 0; q < 8; q++) {
    short8v v[4];
#pragma unroll
    for (int i = 0; i < 4; i++)
      v[i] = *(const short8v*)(zb + (size_t)s[i] * 64 + q * 8);
#pragma unroll
    for (int t = 0; t < 8; t++) {
      float vt[4];
#pragma unroll
      for (int i = 0; i < 4; i++) vt[i] = bf2f(v[i][t]);
#pragma unroll
      for (int fc = 0; fc < 4; fc++) {
        f32x4 wv = *(const f32x4*)&w[(q * 8 + t) * 16 + fc * 4];
#pragma unroll
        for (int i = 0; i < 4; i++) {
          acc[i][fc * 4 + 0] = fmaf(vt[i], wv.x, acc[i][fc * 4 + 0]);
          acc[i][fc * 4 + 1] = fmaf(vt[i], wv.y, acc[i][fc * 4 + 1]);
          acc[i][fc * 4 + 2] = fmaf(vt[i], wv.z, acc[i][fc * 4 + 2]);
          acc[i][fc * 4 + 3] = fmaf(vt[i], wv.w, acc[i][fc * 4 + 3]);
        }
      }
    }
  }
#pragma unroll 2
  for (int q = 0; q < 8; q++) {
    short8v v[4];
#pragma unroll
    for (int i = 0; i < 4; i++)
      v[i] = *(const short8v*)(zb + (size_t)d[i] * 64 + q * 8);
#pragma unroll
    for (int t = 0; t < 8; t++) {
      float vt[4];
#pragma unroll
      for (int i = 0; i < 4; i++) vt[i] = bf2f(v[i][t]);
#pragma unroll
      for (int fc = 0; fc < 4; fc++) {
        f32x4 wv = *(const f32x4*)&w[1024 + (q * 8 + t) * 16 + fc * 4];
#pragma unroll
        for (int i = 0; i < 4; i++) {
          acc[i][fc * 4 + 0] = fmaf(vt[i], wv.x, acc[i][fc * 4 + 0]);
          acc[i][fc * 4 + 1] = fmaf(vt[i], wv.y, acc[i][fc * 4 + 1]);
          acc[i][fc * 4 + 2] = fmaf(vt[i], wv.z, acc[i][fc * 4 + 2]);
          acc[i][fc * 4 + 3] = fmaf(vt[i], wv.w, acc[i][fc * 4 + 3]);
        }
      }
    }
  }
#pragma unroll
  for (int i = 0; i < 4; i++) {
    float4* o4 = (float4*)(eout + (size_t)(base + i * 256) * 16);
    o4[0] = make_float4(acc[i][0], acc[i][1], acc[i][2], acc[i][3]);
    o4[1] = make_float4(acc[i][4], acc[i][5], acc[i][6], acc[i][7]);
    o4[2] = make_float4(acc[i][8], acc[i][9], acc[i][10], acc[i][11]);
    o4[3] = make_float4(acc[i][12], acc[i][13], acc[i][14], acc[i][15]);
  }
}

// ---------------------------------------------------------------- launch
extern "C" void kernel_launch(void* const* d_in, const int* in_sizes, int n_in,
                              void* d_out, int out_size, void* d_ws, size_t ws_size,
                              hipStream_t stream) {
  const float* x      = (const float*)d_in[0];
  const int*   ei     = (const int*)d_in[1];
  const float* w1     = (const float*)d_in[3];
  const float* bn1_g  = (const float*)d_in[5];
  const float* bn1_b  = (const float*)d_in[6];
  const float* w2     = (const float*)d_in[7];
  const float* bn2_g  = (const float*)d_in[9];
  const float* bn2_b  = (const float*)d_in[10];
  const float* w_bin  = (const float*)d_in[11];
  const float* b_bin  = (const float*)d_in[12];
  const float* w_mc   = (const float*)d_in[13];
  const float* b_mc   = (const float*)d_in[14];
  const float* w_cont = (const float*)d_in[15];
  const float* b_cont = (const float*)d_in[16];
  const float* w_edge = (const float*)d_in[17];
  const float* b_edge = (const float*)d_in[18];

  float* out0 = (float*)d_out;
  float* adj  = out0 + (size_t)kN * 30;
  float* eout = adj + (size_t)kN * kN;

  char* wp = (char*)d_ws;
  auto alloc = [&](size_t bytes) {
    char* p = wp;
    wp += (bytes + 255) & ~(size_t)255;
    return p;
  };
  int*   counts  = (int*)alloc((size_t)kN * 4);
  int*   offsets = (int*)alloc((size_t)kN * 4);
  int*   pos     = (int*)alloc((size_t)kN * 4);
  int*   csr_src = (int*)alloc((size_t)kE * 4);
  float* dis     = (float*)alloc((size_t)kN * 4);
  float* sums1   = (float*)alloc(256 * 4);
  float* sums2   = (float*)alloc(128 * 4);
  float* scale1  = (float*)alloc(128 * 4);
  float* shift1  = (float*)alloc(128 * 4);
  float* scale2  = (float*)alloc(64 * 4);
  float* shift2  = (float*)alloc(64 * 4);
  float* hs1     = (float*)alloc((size_t)kN * 128 * 4);
  float* t1      = (float*)alloc((size_t)kN * 128 * 4);
  float* hs2     = (float*)alloc((size_t)kN * 64 * 4);
  float* t2      = (float*)alloc((size_t)kN * 64 * 4);
  float* zf      = (float*)alloc((size_t)kN * 64 * 4);
  __hip_bfloat16* zb = (__hip_bfloat16*)alloc((size_t)kN * 64 * 2);

  const int* esrc = ei;
  const int* edst = ei + kE;

  zero_kernel<<<dim3(64), dim3(256), 0, stream>>>(counts, sums1, sums2);
  hist_kernel<<<dim3(2048), dim3(256), 0, stream>>>(edst, counts);
  scan_kernel<<<dim3(1), dim3(1024), 0, stream>>>(counts, offsets, pos, dis);
  fill_kernel<<<dim3(2048), dim3(256), 0, stream>>>(esrc, edst, pos, csr_src);

  gemm_kernel<128, false><<<dim3(kN / 64), dim3(256), 0, stream>>>(
      x, w1, nullptr, nullptr, dis, hs1);
  agg_kernel<128><<<dim3(kN), dim3(128), 0, stream>>>(hs1, csr_src, offsets, counts, dis, t1);
  stats_kernel<128><<<dim3(256), dim3(256), 0, stream>>>(t1, sums1);
  finalize_kernel<128><<<dim3(1), dim3(128), 0, stream>>>(sums1, bn1_g, bn1_b, scale1, shift1);

  gemm_kernel<64, true><<<dim3(kN / 64), dim3(256), 0, stream>>>(
      t1, w2, scale1, shift1, dis, hs2);
  agg_kernel<64><<<dim3(kN), dim3(64), 0, stream>>>(hs2, csr_src, offsets, counts, dis, t2);
  stats_kernel<64><<<dim3(256), dim3(256), 0, stream>>>(t2, sums2);
  finalize_kernel<64><<<dim3(1), dim3(64), 0, stream>>>(sums2, bn2_g, bn2_b, scale2, shift2);

  applyz_kernel<<<dim3(kN * 64 / 256), dim3(256), 0, stream>>>(t2, scale2, shift2, zf, zb);

  heads_kernel<<<dim3(kN / 256), dim3(256), 0, stream>>>(
      zf, w_bin, b_bin, w_mc, b_mc, w_cont, b_cont, out0);
  adj_kernel<<<dim3(kN / 128, kN / 128), dim3(256), 0, stream>>>((const short*)zb, adj);
  edge_kernel<<<dim3(kE / 1024), dim3(256), 0, stream>>>((const short*)zb, esrc, edst,
                                                         w_edge, b_edge, eout);
}

// Round 5
// 480.683 us; speedup vs baseline: 1.3309x; 1.0147x over previous
//
#include <hip/hip_runtime.h>
#include <hip/hip_bf16.h>
#include <math.h>

// GAE on MI355X. N=16384 nodes, E=524288 edges.
// R5: adj kernel stages the 128x128 fp32 C-tile in LDS and writes with
// fully-coalesced float4 stores (1 KB/wave/instr) instead of 64 B-segmented
// dword scatters from the MFMA fragment layout. Rest identical to R4.

constexpr int kN = 16384;
constexpr int kE = 524288;
constexpr float kEps = 1e-5f;

typedef __attribute__((ext_vector_type(8))) short short8v;   // 8 x bf16
typedef __attribute__((ext_vector_type(4))) float f32x4;

__device__ inline float bf2f(short u) {
  return __uint_as_float(((unsigned)(unsigned short)u) << 16);
}

// ---------------------------------------------------------------- utility
__global__ void zero_kernel(int* counts, float* sums1, float* sums2) {
  int i = blockIdx.x * 256 + threadIdx.x;
  if (i < kN) counts[i] = 0;
  if (i < 256) sums1[i] = 0.f;
  if (i < 128) sums2[i] = 0.f;
}

__global__ void hist_kernel(const int* __restrict__ dst, int* __restrict__ counts) {
  int e = blockIdx.x * 256 + threadIdx.x;
  if (e < kE) atomicAdd(&counts[dst[e]], 1);
}

// Single-block exclusive scan of counts[16384] -> offsets, pos; also dis=rsqrt(deg).
__global__ __launch_bounds__(1024) void scan_kernel(const int* __restrict__ counts,
    int* __restrict__ offsets, int* __restrict__ pos, float* __restrict__ dis) {
  __shared__ int wave_tot[16];
  int tid = threadIdx.x;
  int base = tid * 16;
  int loc[16];
  int s = 0;
#pragma unroll
  for (int i = 0; i < 16; i++) { loc[i] = s; s += counts[base + i]; }
  int lane = tid & 63, wv = tid >> 6;
  int incl = s;
#pragma unroll
  for (int d = 1; d < 64; d <<= 1) {
    int v = __shfl_up(incl, d, 64);
    if (lane >= d) incl += v;
  }
  if (lane == 63) wave_tot[wv] = incl;
  __syncthreads();
  int woff = 0;
  for (int i = 0; i < wv; i++) woff += wave_tot[i];
  int excl = woff + incl - s;
#pragma unroll
  for (int i = 0; i < 16; i++) {
    int o = excl + loc[i];
    offsets[base + i] = o;
    pos[base + i] = o;
    dis[base + i] = rsqrtf((float)counts[base + i] + 1.0f);  // +1 self-loop
  }
}

__global__ void fill_kernel(const int* __restrict__ src, const int* __restrict__ dst,
                            int* __restrict__ pos, int* __restrict__ csr_src) {
  int e = blockIdx.x * 256 + threadIdx.x;
  if (e < kE) {
    int d = dst[e];
    int p = atomicAdd(&pos[d], 1);
    csr_src[p] = src[e];
  }
}

// ---------------------------------------------------------------- fp32 GEMM
template <int BC, bool AFFINE>
__global__ __launch_bounds__(256) void gemm_kernel(
    const float* __restrict__ A, const float* __restrict__ W,
    const float* __restrict__ scl, const float* __restrict__ shf,
    const float* __restrict__ dis, float* __restrict__ out) {
  constexpr int NJ = BC / 16;              // cols per thread (stride 16)
  constexpr int WF4 = (32 * BC) / 4 / 256; // float4 stages of W per thread
  __shared__ float xs[64 * 33];            // 64 rows x 32 k, pad->33
  __shared__ float wsh[32 * BC];
  int tid = threadIdx.x;
  int tx = tid & 15, ty = tid >> 4;
  int r0 = blockIdx.x * 64;
  float acc[4][NJ];
#pragma unroll
  for (int r = 0; r < 4; r++)
#pragma unroll
    for (int j = 0; j < NJ; j++) acc[r][j] = 0.f;

  for (int kb = 0; kb < 128; kb += 32) {
    __syncthreads();
#pragma unroll
    for (int q = 0; q < 2; q++) {
      int f = tid + q * 256;
      int row = f >> 3, kq = f & 7;
      float4 v = *(const float4*)(A + (size_t)(r0 + row) * 128 + kb + kq * 4);
      if (AFFINE) {
        float4 s4 = *(const float4*)(scl + kb + kq * 4);
        float4 h4 = *(const float4*)(shf + kb + kq * 4);
        v.x = fmaxf(0.f, fmaf(v.x, s4.x, h4.x));
        v.y = fmaxf(0.f, fmaf(v.y, s4.y, h4.y));
        v.z = fmaxf(0.f, fmaf(v.z, s4.z, h4.z));
        v.w = fmaxf(0.f, fmaf(v.w, s4.w, h4.w));
      }
      int bb = row * 33 + kq * 4;
      xs[bb + 0] = v.x; xs[bb + 1] = v.y; xs[bb + 2] = v.z; xs[bb + 3] = v.w;
    }
#pragma unroll
    for (int q = 0; q < WF4; q++) {
      int f = tid + q * 256;
      int k = f / (BC / 4), cq = f % (BC / 4);
      *(float4*)&wsh[k * BC + cq * 4] =
          *(const float4*)(W + (size_t)(kb + k) * BC + cq * 4);
    }
    __syncthreads();
#pragma unroll
    for (int kk = 0; kk < 32; kk++) {
      float av[4];
#pragma unroll
      for (int r = 0; r < 4; r++) av[r] = xs[(ty * 4 + r) * 33 + kk];
#pragma unroll
      for (int j = 0; j < NJ; j++) {
        float bv = wsh[kk * BC + tx + j * 16];
#pragma unroll
        for (int r = 0; r < 4; r++) acc[r][j] = fmaf(av[r], bv, acc[r][j]);
      }
    }
  }
#pragma unroll
  for (int r = 0; r < 4; r++) {
    int row = r0 + ty * 4 + r;
    float dr = dis[row];
#pragma unroll
    for (int j = 0; j < NJ; j++)
      out[(size_t)row * BC + tx + j * 16] = acc[r][j] * dr;
  }
}

// ---------------------------------------------------------------- aggregation
template <int C>
__global__ void agg_kernel(const float* __restrict__ hs, const int* __restrict__ csr_src,
                           const int* __restrict__ offsets, const int* __restrict__ counts,
                           const float* __restrict__ dis, float* __restrict__ t) {
  int d = blockIdx.x;
  int c = threadIdx.x;
  float acc = hs[(size_t)d * C + c];  // self-loop
  int s0 = offsets[d];
  int n = counts[d];
  int i = 0;
  for (; i + 4 <= n; i += 4) {
    int sa = csr_src[s0 + i];
    int sb = csr_src[s0 + i + 1];
    int sc = csr_src[s0 + i + 2];
    int sd = csr_src[s0 + i + 3];
    float va = hs[(size_t)sa * C + c];
    float vb = hs[(size_t)sb * C + c];
    float vc = hs[(size_t)sc * C + c];
    float vd = hs[(size_t)sd * C + c];
    acc += va; acc += vb; acc += vc; acc += vd;
  }
  for (; i < n; i++) acc += hs[(size_t)csr_src[s0 + i] * C + c];
  t[(size_t)d * C + c] = acc * dis[d];
}

// ---------------------------------------------------------------- BN
template <int C>
__global__ __launch_bounds__(256) void stats_kernel(const float* __restrict__ t,
                                                    float* __restrict__ sums) {
  constexpr int RP = 256 / C;
  int c = threadIdx.x % C;
  int rr = threadIdx.x / C;
  float s = 0.f, s2 = 0.f;
  for (int r = blockIdx.x * RP + rr; r < kN; r += gridDim.x * RP) {
    float v = t[(size_t)r * C + c];
    s += v;
    s2 += v * v;
  }
  atomicAdd(&sums[c], s);
  atomicAdd(&sums[C + c], s2);
}

template <int C>
__global__ void finalize_kernel(const float* __restrict__ sums, const float* __restrict__ g,
                                const float* __restrict__ b, float* __restrict__ scale,
                                float* __restrict__ shift) {
  int c = threadIdx.x;
  float mean = sums[c] / (float)kN;
  float var = sums[C + c] / (float)kN - mean * mean;
  float inv = rsqrtf(var + kEps);
  float sc = g[c] * inv;
  scale[c] = sc;
  shift[c] = b[c] - mean * sc;
}

// z = relu(t2*scale+shift), stored fp32 and bf16
__global__ void applyz_kernel(const float* __restrict__ t2, const float* __restrict__ scale,
                              const float* __restrict__ shift, float* __restrict__ zf,
                              __hip_bfloat16* __restrict__ zb) {
  int i = blockIdx.x * 256 + threadIdx.x;  // kN*64 total
  int c = i & 63;
  float v = fmaxf(0.f, fmaf(t2[i], scale[c], shift[c]));
  zf[i] = v;
  zb[i] = __float2bfloat16(v);
}

// ---------------------------------------------------------------- heads
__global__ __launch_bounds__(256) void heads_kernel(const float* __restrict__ zf,
    const float* __restrict__ wbin, const float* __restrict__ bbin,
    const float* __restrict__ wmc, const float* __restrict__ bmc,
    const float* __restrict__ wcont, const float* __restrict__ bcont,
    float* __restrict__ out0) {
  __shared__ float wT[30 * 64];
  __shared__ float bias[32];
  int tid = threadIdx.x;
  for (int idx = tid; idx < 1920; idx += 256) {
    int j = idx >> 6, k = idx & 63;
    const float* src = (j < 10) ? wbin : (j < 20) ? wmc : wcont;
    wT[idx] = src[k * 10 + (j % 10)];
  }
  if (tid < 30)
    bias[tid] = (tid < 10) ? bbin[tid] : (tid < 20) ? bmc[tid - 10] : bcont[tid - 20];
  __syncthreads();
  int n = blockIdx.x * 256 + tid;
  float zr[64];
  const float4* z4 = (const float4*)(zf + (size_t)n * 64);
#pragma unroll
  for (int q = 0; q < 16; q++) {
    float4 v = z4[q];
    zr[4 * q] = v.x; zr[4 * q + 1] = v.y; zr[4 * q + 2] = v.z; zr[4 * q + 3] = v.w;
  }
  float acc[30];
#pragma unroll
  for (int j = 0; j < 30; j++) {
    float s = bias[j];
#pragma unroll
    for (int kc = 0; kc < 16; kc++) {
      f32x4 wv = *(const f32x4*)&wT[j * 64 + kc * 4];
      s = fmaf(zr[4 * kc + 0], wv.x, s);
      s = fmaf(zr[4 * kc + 1], wv.y, s);
      s = fmaf(zr[4 * kc + 2], wv.z, s);
      s = fmaf(zr[4 * kc + 3], wv.w, s);
    }
    acc[j] = s;
  }
  float* o = out0 + (size_t)n * 30;
#pragma unroll
  for (int j = 0; j < 10; j++) o[j] = 1.f / (1.f + expf(-acc[j]));
  float m1 = fmaxf(fmaxf(acc[10], acc[11]), fmaxf(acc[12], acc[13]));
  float e1[4], s1 = 0.f;
#pragma unroll
  for (int j = 0; j < 4; j++) { e1[j] = expf(acc[10 + j] - m1); s1 += e1[j]; }
#pragma unroll
  for (int j = 0; j < 4; j++) o[10 + j] = e1[j] / s1;
  float m2 = acc[14];
#pragma unroll
  for (int j = 15; j < 20; j++) m2 = fmaxf(m2, acc[j]);
  float e2[6], s2 = 0.f;
#pragma unroll
  for (int j = 0; j < 6; j++) { e2[j] = expf(acc[14 + j] - m2); s2 += e2[j]; }
#pragma unroll
  for (int j = 0; j < 6; j++) o[14 + j] = e2[j] / s2;
#pragma unroll
  for (int j = 0; j < 10; j++) o[20 + j] = acc[20 + j];
}

// ---------------------------------------------------------------- adj = z z^T (bf16 MFMA)
// MFMA as before; C tile staged in LDS (stride 132), then coalesced float4
// stores: each wave writes 1 KB contiguous per instruction.
__global__ __launch_bounds__(256) void adj_kernel(const short* __restrict__ zb,
                                                  float* __restrict__ adj) {
  __shared__ float cs[128 * 132];
  int tid = threadIdx.x;
  int wid = tid >> 6, lane = tid & 63;
  int li0 = (wid >> 1) * 64;              // local row of wave tile
  int lj0 = (wid & 1) * 64;               // local col of wave tile
  int i0 = blockIdx.x * 128 + li0;
  int j0 = blockIdx.y * 128 + lj0;
  int lr = lane & 15, lg = lane >> 4;
  short8v a[4][2], b[4][2];
#pragma unroll
  for (int mt = 0; mt < 4; mt++)
#pragma unroll
    for (int ks = 0; ks < 2; ks++)
      a[mt][ks] = *(const short8v*)(zb + (size_t)(i0 + mt * 16 + lr) * 64 + ks * 32 + lg * 8);
#pragma unroll
  for (int nt = 0; nt < 4; nt++)
#pragma unroll
    for (int ks = 0; ks < 2; ks++)
      b[nt][ks] = *(const short8v*)(zb + (size_t)(j0 + nt * 16 + lr) * 64 + ks * 32 + lg * 8);
  f32x4 acc[4][4];
#pragma unroll
  for (int mt = 0; mt < 4; mt++)
#pragma unroll
    for (int nt = 0; nt < 4; nt++) {
      f32x4 zz = {0.f, 0.f, 0.f, 0.f};
      acc[mt][nt] = zz;
    }
#pragma unroll
  for (int ks = 0; ks < 2; ks++)
#pragma unroll
    for (int mt = 0; mt < 4; mt++)
#pragma unroll
      for (int nt = 0; nt < 4; nt++)
        acc[mt][nt] = __builtin_amdgcn_mfma_f32_16x16x32_bf16(a[mt][ks], b[nt][ks],
                                                              acc[mt][nt], 0, 0, 0);
  // C/D frag layout: col = lane&15, row = (lane>>4)*4 + reg
#pragma unroll
  for (int mt = 0; mt < 4; mt++)
#pragma unroll
    for (int nt = 0; nt < 4; nt++)
#pragma unroll
      for (int r = 0; r < 4; r++)
        cs[(li0 + mt * 16 + lg * 4 + r) * 132 + lj0 + nt * 16 + lr] = acc[mt][nt][r];
  __syncthreads();
  // coalesced write-out: 16 iters x (8 rows x 32 float4) = 128x128
  int row = tid >> 5;          // 0..7
  int c4 = tid & 31;           // 0..31
  size_t gbase = (size_t)(blockIdx.x * 128 + row) * kN + blockIdx.y * 128 + c4 * 4;
  const float* lbase = &cs[row * 132 + c4 * 4];
#pragma unroll
  for (int it = 0; it < 16; it++) {
    f32x4 v = *(const f32x4*)(lbase + it * 8 * 132);
    *(f32x4*)(adj + gbase + (size_t)it * 8 * kN) = v;
  }
}

// ---------------------------------------------------------------- edge features
// 4 edges per thread: LDS float4 weight broadcasts amortized 4x; bf16 z gathers.
__global__ __launch_bounds__(256) void edge_kernel(const short* __restrict__ zb,
    const int* __restrict__ srcs, const int* __restrict__ dsts,
    const float* __restrict__ we, const float* __restrict__ be,
    float* __restrict__ eout) {
  __shared__ float w[2048];  // 128 x 16
  __shared__ float bb[16];
  int tid = threadIdx.x;
  for (int i = tid; i < 2048; i += 256) w[i] = we[i];
  if (tid < 16) bb[tid] = be[tid];
  __syncthreads();
  int base = blockIdx.x * 1024 + tid;  // 1024 edges per block, kE/1024 = 512 blocks
  int s[4], d[4];
#pragma unroll
  for (int i = 0; i < 4; i++) { s[i] = srcs[base + i * 256]; d[i] = dsts[base + i * 256]; }
  float acc[4][16];
#pragma unroll
  for (int i = 0; i < 4; i++)
#pragma unroll
    for (int f = 0; f < 16; f++) acc[i][f] = bb[f];

#pragma unroll 2
  for (int q = 0; q < 8; q++) {
    short8v v[4];
#pragma unroll
    for (int i = 0; i < 4; i++)
      v[i] = *(const short8v*)(zb + (size_t)s[i] * 64 + q * 8);
#pragma unroll
    for (int t = 0; t < 8; t++) {
      float vt[4];
#pragma unroll
      for (int i = 0; i < 4; i++) vt[i] = bf2f(v[i][t]);
#pragma unroll
      for (int fc = 0; fc < 4; fc++) {
        f32x4 wv = *(const f32x4*)&w[(q * 8 + t) * 16 + fc * 4];
#pragma unroll
        for (int i = 0; i < 4; i++) {
          acc[i][fc * 4 + 0] = fmaf(vt[i], wv.x, acc[i][fc * 4 + 0]);
          acc[i][fc * 4 + 1] = fmaf(vt[i], wv.y, acc[i][fc * 4 + 1]);
          acc[i][fc * 4 + 2] = fmaf(vt[i], wv.z, acc[i][fc * 4 + 2]);
          acc[i][fc * 4 + 3] = fmaf(vt[i], wv.w, acc[i][fc * 4 + 3]);
        }
      }
    }
  }
#pragma unroll 2
  for (int q = 0; q < 8; q++) {
    short8v v[4];
#pragma unroll
    for (int i = 0; i < 4; i++)
      v[i] = *(const short8v*)(zb + (size_t)d[i] * 64 + q * 8);
#pragma unroll
    for (int t = 0; t < 8; t++) {
      float vt[4];
#pragma unroll
      for (int i = 0; i < 4; i++) vt[i] = bf2f(v[i][t]);
#pragma unroll
      for (int fc = 0; fc < 4; fc++) {
        f32x4 wv = *(const f32x4*)&w[1024 + (q * 8 + t) * 16 + fc * 4];
#pragma unroll
        for (int i = 0; i < 4; i++) {
          acc[i][fc * 4 + 0] = fmaf(vt[i], wv.x, acc[i][fc * 4 + 0]);
          acc[i][fc * 4 + 1] = fmaf(vt[i], wv.y, acc[i][fc * 4 + 1]);
          acc[i][fc * 4 + 2] = fmaf(vt[i], wv.z, acc[i][fc * 4 + 2]);
          acc[i][fc * 4 + 3] = fmaf(vt[i], wv.w, acc[i][fc * 4 + 3]);
        }
      }
    }
  }
#pragma unroll
  for (int i = 0; i < 4; i++) {
    float4* o4 = (float4*)(eout + (size_t)(base + i * 256) * 16);
    o4[0] = make_float4(acc[i][0], acc[i][1], acc[i][2], acc[i][3]);
    o4[1] = make_float4(acc[i][4], acc[i][5], acc[i][6], acc[i][7]);
    o4[2] = make_float4(acc[i][8], acc[i][9], acc[i][10], acc[i][11]);
    o4[3] = make_float4(acc[i][12], acc[i][13], acc[i][14], acc[i][15]);
  }
}

// ---------------------------------------------------------------- launch
extern "C" void kernel_launch(void* const* d_in, const int* in_sizes, int n_in,
                              void* d_out, int out_size, void* d_ws, size_t ws_size,
                              hipStream_t stream) {
  const float* x      = (const float*)d_in[0];
  const int*   ei     = (const int*)d_in[1];
  const float* w1     = (const float*)d_in[3];
  const float* bn1_g  = (const float*)d_in[5];
  const float* bn1_b  = (const float*)d_in[6];
  const float* w2     = (const float*)d_in[7];
  const float* bn2_g  = (const float*)d_in[9];
  const float* bn2_b  = (const float*)d_in[10];
  const float* w_bin  = (const float*)d_in[11];
  const float* b_bin  = (const float*)d_in[12];
  const float* w_mc   = (const float*)d_in[13];
  const float* b_mc   = (const float*)d_in[14];
  const float* w_cont = (const float*)d_in[15];
  const float* b_cont = (const float*)d_in[16];
  const float* w_edge = (const float*)d_in[17];
  const float* b_edge = (const float*)d_in[18];

  float* out0 = (float*)d_out;
  float* adj  = out0 + (size_t)kN * 30;
  float* eout = adj + (size_t)kN * kN;

  char* wp = (char*)d_ws;
  auto alloc = [&](size_t bytes) {
    char* p = wp;
    wp += (bytes + 255) & ~(size_t)255;
    return p;
  };
  int*   counts  = (int*)alloc((size_t)kN * 4);
  int*   offsets = (int*)alloc((size_t)kN * 4);
  int*   pos     = (int*)alloc((size_t)kN * 4);
  int*   csr_src = (int*)alloc((size_t)kE * 4);
  float* dis     = (float*)alloc((size_t)kN * 4);
  float* sums1   = (float*)alloc(256 * 4);
  float* sums2   = (float*)alloc(128 * 4);
  float* scale1  = (float*)alloc(128 * 4);
  float* shift1  = (float*)alloc(128 * 4);
  float* scale2  = (float*)alloc(64 * 4);
  float* shift2  = (float*)alloc(64 * 4);
  float* hs1     = (float*)alloc((size_t)kN * 128 * 4);
  float* t1      = (float*)alloc((size_t)kN * 128 * 4);
  float* hs2     = (float*)alloc((size_t)kN * 64 * 4);
  float* t2      = (float*)alloc((size_t)kN * 64 * 4);
  float* zf      = (float*)alloc((size_t)kN * 64 * 4);
  __hip_bfloat16* zb = (__hip_bfloat16*)alloc((size_t)kN * 64 * 2);

  const int* esrc = ei;
  const int* edst = ei + kE;

  zero_kernel<<<dim3(64), dim3(256), 0, stream>>>(counts, sums1, sums2);
  hist_kernel<<<dim3(2048), dim3(256), 0, stream>>>(edst, counts);
  scan_kernel<<<dim3(1), dim3(1024), 0, stream>>>(counts, offsets, pos, dis);
  fill_kernel<<<dim3(2048), dim3(256), 0, stream>>>(esrc, edst, pos, csr_src);

  gemm_kernel<128, false><<<dim3(kN / 64), dim3(256), 0, stream>>>(
      x, w1, nullptr, nullptr, dis, hs1);
  agg_kernel<128><<<dim3(kN), dim3(128), 0, stream>>>(hs1, csr_src, offsets, counts, dis, t1);
  stats_kernel<128><<<dim3(256), dim3(256), 0, stream>>>(t1, sums1);
  finalize_kernel<128><<<dim3(1), dim3(128), 0, stream>>>(sums1, bn1_g, bn1_b, scale1, shift1);

  gemm_kernel<64, true><<<dim3(kN / 64), dim3(256), 0, stream>>>(
      t1, w2, scale1, shift1, dis, hs2);
  agg_kernel<64><<<dim3(kN), dim3(64), 0, stream>>>(hs2, csr_src, offsets, counts, dis, t2);
  stats_kernel<64><<<dim3(256), dim3(256), 0, stream>>>(t2, sums2);
  finalize_kernel<64><<<dim3(1), dim3(64), 0, stream>>>(sums2, bn2_g, bn2_b, scale2, shift2);

  applyz_kernel<<<dim3(kN * 64 / 256), dim3(256), 0, stream>>>(t2, scale2, shift2, zf, zb);

  heads_kernel<<<dim3(kN / 256), dim3(256), 0, stream>>>(
      zf, w_bin, b_bin, w_mc, b_mc, w_cont, b_cont, out0);
  adj_kernel<<<dim3(kN / 128, kN / 128), dim3(256), 0, stream>>>((const short*)zb, adj);
  edge_kernel<<<dim3(kE / 1024), dim3(256), 0, stream>>>((const short*)zb, esrc, edst,
                                                         w_edge, b_edge, eout);
}

// Round 6
// 442.229 us; speedup vs baseline: 1.4467x; 1.0870x over previous
//
#include <hip/hip_runtime.h>
#include <hip/hip_bf16.h>
#include <math.h>

// GAE on MI355X. N=16384 nodes, E=524288 edges.
// R6: bf16 intermediates (hs1/t1/hs2) halve aggregation gather traffic;
// edge-feature kernel rewritten as MFMA GEMM with pre-swizzled B fragments;
// finalize kernels fused into gemm2 / applyz (14 launches).

constexpr int kN = 16384;
constexpr int kE = 524288;
constexpr float kEps = 1e-5f;

typedef __attribute__((ext_vector_type(8))) short short8v;   // 8 x bf16
typedef __attribute__((ext_vector_type(4))) float f32x4;

__device__ inline float bf2f(unsigned short u) {
  return __uint_as_float(((unsigned)u) << 16);
}

// ---------------------------------------------------------------- utility
// zero counters/sums + convert w_edge to bf16 in MFMA B-fragment layout.
__global__ void zero_kernel(int* counts, float* sums1, float* sums2,
                            const float* __restrict__ we, __hip_bfloat16* wfr) {
  int i = blockIdx.x * 256 + threadIdx.x;
  if (i < kN) counts[i] = 0;
  if (i < 256) sums1[i] = 0.f;
  if (i < 128) sums2[i] = 0.f;
  if (i < 2048) {
    // frag f (0:src-k0, 1:src-k1, 2:dst-k0, 3:dst-k1), lane l, elem j
    int f = i >> 9, l = (i >> 3) & 63, j = i & 7;
    int lr = l & 15, lg = l >> 4;
    int krow = f * 32 + lg * 8 + j;     // 0..127 row of w_edge
    wfr[i] = __float2bfloat16(we[krow * 16 + lr]);
  }
}

__global__ void hist_kernel(const int* __restrict__ dst, int* __restrict__ counts) {
  int e = blockIdx.x * 256 + threadIdx.x;
  if (e < kE) atomicAdd(&counts[dst[e]], 1);
}

// Single-block exclusive scan of counts[16384] -> offsets, pos; also dis=rsqrt(deg).
__global__ __launch_bounds__(1024) void scan_kernel(const int* __restrict__ counts,
    int* __restrict__ offsets, int* __restrict__ pos, float* __restrict__ dis) {
  __shared__ int wave_tot[16];
  int tid = threadIdx.x;
  int base = tid * 16;
  int loc[16];
  int s = 0;
#pragma unroll
  for (int i = 0; i < 16; i++) { loc[i] = s; s += counts[base + i]; }
  int lane = tid & 63, wv = tid >> 6;
  int incl = s;
#pragma unroll
  for (int d = 1; d < 64; d <<= 1) {
    int v = __shfl_up(incl, d, 64);
    if (lane >= d) incl += v;
  }
  if (lane == 63) wave_tot[wv] = incl;
  __syncthreads();
  int woff = 0;
  for (int i = 0; i < wv; i++) woff += wave_tot[i];
  int excl = woff + incl - s;
#pragma unroll
  for (int i = 0; i < 16; i++) {
    int o = excl + loc[i];
    offsets[base + i] = o;
    pos[base + i] = o;
    dis[base + i] = rsqrtf((float)counts[base + i] + 1.0f);  // +1 self-loop
  }
}

__global__ void fill_kernel(const int* __restrict__ src, const int* __restrict__ dst,
                            int* __restrict__ pos, int* __restrict__ csr_src) {
  int e = blockIdx.x * 256 + threadIdx.x;
  if (e < kE) {
    int d = dst[e];
    int p = atomicAdd(&pos[d], 1);
    csr_src[p] = src[e];
  }
}

// ---------------------------------------------------------------- GEMM layer 1
// hs1[row][c] = dis[row] * sum_k x(row,k) * W1[k][c], bf16 output. BC=128.
__global__ __launch_bounds__(256) void gemm1_kernel(
    const float* __restrict__ A, const float* __restrict__ W,
    const float* __restrict__ dis, __hip_bfloat16* __restrict__ out) {
  constexpr int BC = 128, NJ = 8, WF4 = 4;
  __shared__ float xs[64 * 33];
  __shared__ float wsh[32 * BC];
  int tid = threadIdx.x;
  int tx = tid & 15, ty = tid >> 4;
  int r0 = blockIdx.x * 64;
  float acc[4][NJ];
#pragma unroll
  for (int r = 0; r < 4; r++)
#pragma unroll
    for (int j = 0; j < NJ; j++) acc[r][j] = 0.f;

  for (int kb = 0; kb < 128; kb += 32) {
    __syncthreads();
#pragma unroll
    for (int q = 0; q < 2; q++) {
      int f = tid + q * 256;
      int row = f >> 3, kq = f & 7;
      float4 v = *(const float4*)(A + (size_t)(r0 + row) * 128 + kb + kq * 4);
      int bb = row * 33 + kq * 4;
      xs[bb + 0] = v.x; xs[bb + 1] = v.y; xs[bb + 2] = v.z; xs[bb + 3] = v.w;
    }
#pragma unroll
    for (int q = 0; q < WF4; q++) {
      int f = tid + q * 256;
      int k = f / (BC / 4), cq = f % (BC / 4);
      *(float4*)&wsh[k * BC + cq * 4] =
          *(const float4*)(W + (size_t)(kb + k) * BC + cq * 4);
    }
    __syncthreads();
#pragma unroll
    for (int kk = 0; kk < 32; kk++) {
      float av[4];
#pragma unroll
      for (int r = 0; r < 4; r++) av[r] = xs[(ty * 4 + r) * 33 + kk];
#pragma unroll
      for (int j = 0; j < NJ; j++) {
        float bv = wsh[kk * BC + tx + j * 16];
#pragma unroll
        for (int r = 0; r < 4; r++) acc[r][j] = fmaf(av[r], bv, acc[r][j]);
      }
    }
  }
#pragma unroll
  for (int r = 0; r < 4; r++) {
    int row = r0 + ty * 4 + r;
    float dr = dis[row];
#pragma unroll
    for (int j = 0; j < NJ; j++)
      out[(size_t)row * BC + tx + j * 16] = __float2bfloat16(acc[r][j] * dr);
  }
}

// ---------------------------------------------------------------- GEMM layer 2
// A = t1 (bf16); BN1 scale/shift computed per-block from sums1; relu; K=128,
// BC=64; output hs2 bf16 scaled by dis.
__global__ __launch_bounds__(256) void gemm2_kernel(
    const unsigned short* __restrict__ A, const float* __restrict__ W,
    const float* __restrict__ sums, const float* __restrict__ g,
    const float* __restrict__ b, const float* __restrict__ dis,
    __hip_bfloat16* __restrict__ out) {
  constexpr int BC = 64, NJ = 4, WF4 = 2;
  __shared__ float xs[64 * 33];
  __shared__ float wsh[32 * BC];
  __shared__ float s_scl[128], s_shf[128];
  int tid = threadIdx.x;
  if (tid < 128) {
    float mean = sums[tid] / (float)kN;
    float var = sums[128 + tid] / (float)kN - mean * mean;
    float inv = rsqrtf(var + kEps);
    float sc = g[tid] * inv;
    s_scl[tid] = sc;
    s_shf[tid] = b[tid] - mean * sc;
  }
  int tx = tid & 15, ty = tid >> 4;
  int r0 = blockIdx.x * 64;
  float acc[4][NJ];
#pragma unroll
  for (int r = 0; r < 4; r++)
#pragma unroll
    for (int j = 0; j < NJ; j++) acc[r][j] = 0.f;

  for (int kb = 0; kb < 128; kb += 32) {
    __syncthreads();
    {
      int row = tid >> 2, kq = tid & 3;  // 64 rows x 4 chunks of 8 k
      short8v v8 = *(const short8v*)(A + (size_t)(r0 + row) * 128 + kb + kq * 8);
      int bb = row * 33 + kq * 8;
#pragma unroll
      for (int j = 0; j < 8; j++) {
        int c = kb + kq * 8 + j;
        float v = bf2f((unsigned short)v8[j]);
        xs[bb + j] = fmaxf(0.f, fmaf(v, s_scl[c], s_shf[c]));
      }
    }
#pragma unroll
    for (int q = 0; q < WF4; q++) {
      int f = tid + q * 256;
      int k = f / (BC / 4), cq = f % (BC / 4);
      *(float4*)&wsh[k * BC + cq * 4] =
          *(const float4*)(W + (size_t)(kb + k) * BC + cq * 4);
    }
    __syncthreads();
#pragma unroll
    for (int kk = 0; kk < 32; kk++) {
      float av[4];
#pragma unroll
      for (int r = 0; r < 4; r++) av[r] = xs[(ty * 4 + r) * 33 + kk];
#pragma unroll
      for (int j = 0; j < NJ; j++) {
        float bv = wsh[kk * BC + tx + j * 16];
#pragma unroll
        for (int r = 0; r < 4; r++) acc[r][j] = fmaf(av[r], bv, acc[r][j]);
      }
    }
  }
#pragma unroll
  for (int r = 0; r < 4; r++) {
    int row = r0 + ty * 4 + r;
    float dr = dis[row];
#pragma unroll
    for (int j = 0; j < NJ; j++)
      out[(size_t)row * BC + tx + j * 16] = __float2bfloat16(acc[r][j] * dr);
  }
}

// ---------------------------------------------------------------- aggregation
// t[d][c] = dis[d]*(hs[d][c] + sum_src hs[src][c]); bf16 gathers, fp32 accum.
template <int C, bool OBF16>
__global__ void agg_kernel(const unsigned short* __restrict__ hs,
                           const int* __restrict__ csr_src, const int* __restrict__ offsets,
                           const int* __restrict__ counts, const float* __restrict__ dis,
                           void* __restrict__ tout) {
  int d = blockIdx.x;
  int c = threadIdx.x;
  float acc = bf2f(hs[(size_t)d * C + c]);  // self-loop
  int s0 = offsets[d];
  int n = counts[d];
  int i = 0;
  for (; i + 4 <= n; i += 4) {
    int sa = csr_src[s0 + i];
    int sb = csr_src[s0 + i + 1];
    int sc = csr_src[s0 + i + 2];
    int sd = csr_src[s0 + i + 3];
    float va = bf2f(hs[(size_t)sa * C + c]);
    float vb = bf2f(hs[(size_t)sb * C + c]);
    float vc = bf2f(hs[(size_t)sc * C + c]);
    float vd = bf2f(hs[(size_t)sd * C + c]);
    acc += va; acc += vb; acc += vc; acc += vd;
  }
  for (; i < n; i++) acc += bf2f(hs[(size_t)csr_src[s0 + i] * C + c]);
  float r = acc * dis[d];
  if constexpr (OBF16)
    ((__hip_bfloat16*)tout)[(size_t)d * C + c] = __float2bfloat16(r);
  else
    ((float*)tout)[(size_t)d * C + c] = r;
}

// ---------------------------------------------------------------- BN stats
template <int C, bool BF16>
__global__ __launch_bounds__(256) void stats_kernel(const void* __restrict__ t,
                                                    float* __restrict__ sums) {
  constexpr int RP = 256 / C;
  int c = threadIdx.x % C;
  int rr = threadIdx.x / C;
  float s = 0.f, s2 = 0.f;
  for (int r = blockIdx.x * RP + rr; r < kN; r += gridDim.x * RP) {
    float v;
    if constexpr (BF16) v = bf2f(((const unsigned short*)t)[(size_t)r * C + c]);
    else v = ((const float*)t)[(size_t)r * C + c];
    s += v;
    s2 += v * v;
  }
  atomicAdd(&sums[c], s);
  atomicAdd(&sums[C + c], s2);
}

// z = relu(t2*scale+shift); BN2 finalize fused (per-block). fp32 + bf16 out.
__global__ __launch_bounds__(256) void applyz_kernel(const float* __restrict__ t2,
    const float* __restrict__ sums, const float* __restrict__ g,
    const float* __restrict__ b, float* __restrict__ zf,
    __hip_bfloat16* __restrict__ zb) {
  __shared__ float s_scl[64], s_shf[64];
  int tid = threadIdx.x;
  if (tid < 64) {
    float mean = sums[tid] / (float)kN;
    float var = sums[64 + tid] / (float)kN - mean * mean;
    float inv = rsqrtf(var + kEps);
    float sc = g[tid] * inv;
    s_scl[tid] = sc;
    s_shf[tid] = b[tid] - mean * sc;
  }
  __syncthreads();
  int i = blockIdx.x * 256 + tid;  // kN*64 total
  int c = i & 63;
  float v = fmaxf(0.f, fmaf(t2[i], s_scl[c], s_shf[c]));
  zf[i] = v;
  zb[i] = __float2bfloat16(v);
}

// ---------------------------------------------------------------- heads
__global__ __launch_bounds__(256) void heads_kernel(const float* __restrict__ zf,
    const float* __restrict__ wbin, const float* __restrict__ bbin,
    const float* __restrict__ wmc, const float* __restrict__ bmc,
    const float* __restrict__ wcont, const float* __restrict__ bcont,
    float* __restrict__ out0) {
  __shared__ float wT[30 * 64];
  __shared__ float bias[32];
  int tid = threadIdx.x;
  for (int idx = tid; idx < 1920; idx += 256) {
    int j = idx >> 6, k = idx & 63;
    const float* src = (j < 10) ? wbin : (j < 20) ? wmc : wcont;
    wT[idx] = src[k * 10 + (j % 10)];
  }
  if (tid < 30)
    bias[tid] = (tid < 10) ? bbin[tid] : (tid < 20) ? bmc[tid - 10] : bcont[tid - 20];
  __syncthreads();
  int n = blockIdx.x * 256 + tid;
  float zr[64];
  const float4* z4 = (const float4*)(zf + (size_t)n * 64);
#pragma unroll
  for (int q = 0; q < 16; q++) {
    float4 v = z4[q];
    zr[4 * q] = v.x; zr[4 * q + 1] = v.y; zr[4 * q + 2] = v.z; zr[4 * q + 3] = v.w;
  }
  float acc[30];
#pragma unroll
  for (int j = 0; j < 30; j++) {
    float s = bias[j];
#pragma unroll
    for (int kc = 0; kc < 16; kc++) {
      f32x4 wv = *(const f32x4*)&wT[j * 64 + kc * 4];
      s = fmaf(zr[4 * kc + 0], wv.x, s);
      s = fmaf(zr[4 * kc + 1], wv.y, s);
      s = fmaf(zr[4 * kc + 2], wv.z, s);
      s = fmaf(zr[4 * kc + 3], wv.w, s);
    }
    acc[j] = s;
  }
  float* o = out0 + (size_t)n * 30;
#pragma unroll
  for (int j = 0; j < 10; j++) o[j] = 1.f / (1.f + expf(-acc[j]));
  float m1 = fmaxf(fmaxf(acc[10], acc[11]), fmaxf(acc[12], acc[13]));
  float e1[4], s1 = 0.f;
#pragma unroll
  for (int j = 0; j < 4; j++) { e1[j] = expf(acc[10 + j] - m1); s1 += e1[j]; }
#pragma unroll
  for (int j = 0; j < 4; j++) o[10 + j] = e1[j] / s1;
  float m2 = acc[14];
#pragma unroll
  for (int j = 15; j < 20; j++) m2 = fmaxf(m2, acc[j]);
  float e2[6], s2 = 0.f;
#pragma unroll
  for (int j = 0; j < 6; j++) { e2[j] = expf(acc[14 + j] - m2); s2 += e2[j]; }
#pragma unroll
  for (int j = 0; j < 6; j++) o[14 + j] = e2[j] / s2;
#pragma unroll
  for (int j = 0; j < 10; j++) o[20 + j] = acc[20 + j];
}

// ---------------------------------------------------------------- adj = z z^T (bf16 MFMA)
// MFMA + LDS-staged coalesced float4 write-out (R5, kept).
__global__ __launch_bounds__(256) void adj_kernel(const short* __restrict__ zb,
                                                  float* __restrict__ adj) {
  __shared__ float cs[128 * 132];
  int tid = threadIdx.x;
  int wid = tid >> 6, lane = tid & 63;
  int li0 = (wid >> 1) * 64;
  int lj0 = (wid & 1) * 64;
  int i0 = blockIdx.x * 128 + li0;
  int j0 = blockIdx.y * 128 + lj0;
  int lr = lane & 15, lg = lane >> 4;
  short8v a[4][2], b[4][2];
#pragma unroll
  for (int mt = 0; mt < 4; mt++)
#pragma unroll
    for (int ks = 0; ks < 2; ks++)
      a[mt][ks] = *(const short8v*)(zb + (size_t)(i0 + mt * 16 + lr) * 64 + ks * 32 + lg * 8);
#pragma unroll
  for (int nt = 0; nt < 4; nt++)
#pragma unroll
    for (int ks = 0; ks < 2; ks++)
      b[nt][ks] = *(const short8v*)(zb + (size_t)(j0 + nt * 16 + lr) * 64 + ks * 32 + lg * 8);
  f32x4 acc[4][4];
#pragma unroll
  for (int mt = 0; mt < 4; mt++)
#pragma unroll
    for (int nt = 0; nt < 4; nt++) {
      f32x4 zz = {0.f, 0.f, 0.f, 0.f};
      acc[mt][nt] = zz;
    }
#pragma unroll
  for (int ks = 0; ks < 2; ks++)
#pragma unroll
    for (int mt = 0; mt < 4; mt++)
#pragma unroll
      for (int nt = 0; nt < 4; nt++)
        acc[mt][nt] = __builtin_amdgcn_mfma_f32_16x16x32_bf16(a[mt][ks], b[nt][ks],
                                                              acc[mt][nt], 0, 0, 0);
#pragma unroll
  for (int mt = 0; mt < 4; mt++)
#pragma unroll
    for (int nt = 0; nt < 4; nt++)
#pragma unroll
      for (int r = 0; r < 4; r++)
        cs[(li0 + mt * 16 + lg * 4 + r) * 132 + lj0 + nt * 16 + lr] = acc[mt][nt][r];
  __syncthreads();
  int row = tid >> 5;
  int c4 = tid & 31;
  size_t gbase = (size_t)(blockIdx.x * 128 + row) * kN + blockIdx.y * 128 + c4 * 4;
  const float* lbase = &cs[row * 132 + c4 * 4];
#pragma unroll
  for (int it = 0; it < 16; it++) {
    f32x4 v = *(const f32x4*)(lbase + it * 8 * 132);
    *(f32x4*)(adj + gbase + (size_t)it * 8 * kN) = v;
  }
}

// ---------------------------------------------------------------- edge features (MFMA)
// ef[e] = z[src]@We_top + z[dst]@We_bot + be.  Per wave-tile: 16 edges x 16
// outs, K=64 per side -> 4 MFMA. B frags pre-swizzled (wfr). 8 tiles/wave.
__global__ __launch_bounds__(256) void edge_mfma_kernel(const short* __restrict__ zb,
    const int* __restrict__ srcs, const int* __restrict__ dsts,
    const short* __restrict__ wfr, const float* __restrict__ be,
    float* __restrict__ eout) {
  int tid = threadIdx.x;
  int wv = tid >> 6, lane = tid & 63;
  int gw = blockIdx.x * 4 + wv;          // 4096 waves total
  int lr = lane & 15, lg = lane >> 4;
  short8v bfr[4];
#pragma unroll
  for (int f = 0; f < 4; f++)
    bfr[f] = *(const short8v*)(wfr + ((size_t)f * 64 + lane) * 8);
  float bias = be[lr];
  for (int t = 0; t < 8; t++) {
    int e0 = (gw * 8 + t) * 16;
    int se = srcs[e0 + lr], de = dsts[e0 + lr];
    short8v a0 = *(const short8v*)(zb + (size_t)se * 64 + lg * 8);
    short8v a1 = *(const short8v*)(zb + (size_t)se * 64 + 32 + lg * 8);
    short8v a2 = *(const short8v*)(zb + (size_t)de * 64 + lg * 8);
    short8v a3 = *(const short8v*)(zb + (size_t)de * 64 + 32 + lg * 8);
    f32x4 acc = {0.f, 0.f, 0.f, 0.f};
    acc = __builtin_amdgcn_mfma_f32_16x16x32_bf16(a0, bfr[0], acc, 0, 0, 0);
    acc = __builtin_amdgcn_mfma_f32_16x16x32_bf16(a1, bfr[1], acc, 0, 0, 0);
    acc = __builtin_amdgcn_mfma_f32_16x16x32_bf16(a2, bfr[2], acc, 0, 0, 0);
    acc = __builtin_amdgcn_mfma_f32_16x16x32_bf16(a3, bfr[3], acc, 0, 0, 0);
#pragma unroll
    for (int r = 0; r < 4; r++)
      eout[(size_t)(e0 + lg * 4 + r) * 16 + lr] = acc[r] + bias;
  }
}

// ---------------------------------------------------------------- launch
extern "C" void kernel_launch(void* const* d_in, const int* in_sizes, int n_in,
                              void* d_out, int out_size, void* d_ws, size_t ws_size,
                              hipStream_t stream) {
  const float* x      = (const float*)d_in[0];
  const int*   ei     = (const int*)d_in[1];
  const float* w1     = (const float*)d_in[3];
  const float* bn1_g  = (const float*)d_in[5];
  const float* bn1_b  = (const float*)d_in[6];
  const float* w2     = (const float*)d_in[7];
  const float* bn2_g  = (const float*)d_in[9];
  const float* bn2_b  = (const float*)d_in[10];
  const float* w_bin  = (const float*)d_in[11];
  const float* b_bin  = (const float*)d_in[12];
  const float* w_mc   = (const float*)d_in[13];
  const float* b_mc   = (const float*)d_in[14];
  const float* w_cont = (const float*)d_in[15];
  const float* b_cont = (const float*)d_in[16];
  const float* w_edge = (const float*)d_in[17];
  const float* b_edge = (const float*)d_in[18];

  float* out0 = (float*)d_out;
  float* adj  = out0 + (size_t)kN * 30;
  float* eout = adj + (size_t)kN * kN;

  char* wp = (char*)d_ws;
  auto alloc = [&](size_t bytes) {
    char* p = wp;
    wp += (bytes + 255) & ~(size_t)255;
    return p;
  };
  int*   counts  = (int*)alloc((size_t)kN * 4);
  int*   offsets = (int*)alloc((size_t)kN * 4);
  int*   pos     = (int*)alloc((size_t)kN * 4);
  int*   csr_src = (int*)alloc((size_t)kE * 4);
  float* dis     = (float*)alloc((size_t)kN * 4);
  float* sums1   = (float*)alloc(256 * 4);
  float* sums2   = (float*)alloc(128 * 4);
  __hip_bfloat16* hs1 = (__hip_bfloat16*)alloc((size_t)kN * 128 * 2);
  __hip_bfloat16* t1  = (__hip_bfloat16*)alloc((size_t)kN * 128 * 2);
  __hip_bfloat16* hs2 = (__hip_bfloat16*)alloc((size_t)kN * 64 * 2);
  float* t2      = (float*)alloc((size_t)kN * 64 * 4);
  float* zf      = (float*)alloc((size_t)kN * 64 * 4);
  __hip_bfloat16* zb  = (__hip_bfloat16*)alloc((size_t)kN * 64 * 2);
  __hip_bfloat16* wfr = (__hip_bfloat16*)alloc(2048 * 2);

  const int* esrc = ei;
  const int* edst = ei + kE;

  zero_kernel<<<dim3(64), dim3(256), 0, stream>>>(counts, sums1, sums2, w_edge, wfr);
  hist_kernel<<<dim3(2048), dim3(256), 0, stream>>>(edst, counts);
  scan_kernel<<<dim3(1), dim3(1024), 0, stream>>>(counts, offsets, pos, dis);
  fill_kernel<<<dim3(2048), dim3(256), 0, stream>>>(esrc, edst, pos, csr_src);

  gemm1_kernel<<<dim3(kN / 64), dim3(256), 0, stream>>>(x, w1, dis, hs1);
  agg_kernel<128, true><<<dim3(kN), dim3(128), 0, stream>>>(
      (const unsigned short*)hs1, csr_src, offsets, counts, dis, t1);
  stats_kernel<128, true><<<dim3(256), dim3(256), 0, stream>>>(t1, sums1);

  gemm2_kernel<<<dim3(kN / 64), dim3(256), 0, stream>>>(
      (const unsigned short*)t1, w2, sums1, bn1_g, bn1_b, dis, hs2);
  agg_kernel<64, false><<<dim3(kN), dim3(64), 0, stream>>>(
      (const unsigned short*)hs2, csr_src, offsets, counts, dis, t2);
  stats_kernel<64, false><<<dim3(256), dim3(256), 0, stream>>>(t2, sums2);

  applyz_kernel<<<dim3(kN * 64 / 256), dim3(256), 0, stream>>>(
      t2, sums2, bn2_g, bn2_b, zf, zb);

  heads_kernel<<<dim3(kN / 256), dim3(256), 0, stream>>>(
      zf, w_bin, b_bin, w_mc, b_mc, w_cont, b_cont, out0);
  adj_kernel<<<dim3(kN / 128, kN / 128), dim3(256), 0, stream>>>((const short*)zb, adj);
  edge_mfma_kernel<<<dim3(1024), dim3(256), 0, stream>>>(
      (const short*)zb, esrc, edst, (const short*)wfr, b_edge, eout);
}

// Round 7
// 430.142 us; speedup vs baseline: 1.4873x; 1.0281x over previous
//
#include <hip/hip_runtime.h>
#include <hip/hip_bf16.h>
#include <math.h>

// GAE on MI355X. N=16384 nodes, E=524288 edges.
// R7: wave-structured vectorized aggregation (short8 row gathers, lane-group
// parallel edges, shfl reduce); applyz+heads fused (zf eliminated);
// edge MFMA kernel writes via per-wave LDS staging (1 KB coalesced stores).

constexpr int kN = 16384;
constexpr int kE = 524288;
constexpr float kEps = 1e-5f;

typedef __attribute__((ext_vector_type(8))) short short8v;   // 8 x bf16
typedef __attribute__((ext_vector_type(4))) float f32x4;

__device__ inline float bf2f(unsigned short u) {
  return __uint_as_float(((unsigned)u) << 16);
}
__device__ inline unsigned short f2bf(float f) {  // RNE
  unsigned u = __float_as_uint(f);
  return (unsigned short)((u + 0x7fff + ((u >> 16) & 1)) >> 16);
}

// ---------------------------------------------------------------- utility
// zero counters/sums + convert w_edge to bf16 in MFMA B-fragment layout.
__global__ void zero_kernel(int* counts, float* sums1, float* sums2,
                            const float* __restrict__ we, __hip_bfloat16* wfr) {
  int i = blockIdx.x * 256 + threadIdx.x;
  if (i < kN) counts[i] = 0;
  if (i < 256) sums1[i] = 0.f;
  if (i < 128) sums2[i] = 0.f;
  if (i < 2048) {
    int f = i >> 9, l = (i >> 3) & 63, j = i & 7;
    int lr = l & 15, lg = l >> 4;
    int krow = f * 32 + lg * 8 + j;
    wfr[i] = __float2bfloat16(we[krow * 16 + lr]);
  }
}

__global__ void hist_kernel(const int* __restrict__ dst, int* __restrict__ counts) {
  int e = blockIdx.x * 256 + threadIdx.x;
  if (e < kE) atomicAdd(&counts[dst[e]], 1);
}

// Single-block exclusive scan of counts[16384] -> offsets, pos; also dis=rsqrt(deg).
__global__ __launch_bounds__(1024) void scan_kernel(const int* __restrict__ counts,
    int* __restrict__ offsets, int* __restrict__ pos, float* __restrict__ dis) {
  __shared__ int wave_tot[16];
  int tid = threadIdx.x;
  int base = tid * 16;
  int loc[16];
  int s = 0;
#pragma unroll
  for (int i = 0; i < 16; i++) { loc[i] = s; s += counts[base + i]; }
  int lane = tid & 63, wv = tid >> 6;
  int incl = s;
#pragma unroll
  for (int d = 1; d < 64; d <<= 1) {
    int v = __shfl_up(incl, d, 64);
    if (lane >= d) incl += v;
  }
  if (lane == 63) wave_tot[wv] = incl;
  __syncthreads();
  int woff = 0;
  for (int i = 0; i < wv; i++) woff += wave_tot[i];
  int excl = woff + incl - s;
#pragma unroll
  for (int i = 0; i < 16; i++) {
    int o = excl + loc[i];
    offsets[base + i] = o;
    pos[base + i] = o;
    dis[base + i] = rsqrtf((float)counts[base + i] + 1.0f);  // +1 self-loop
  }
}

__global__ void fill_kernel(const int* __restrict__ src, const int* __restrict__ dst,
                            int* __restrict__ pos, int* __restrict__ csr_src) {
  int e = blockIdx.x * 256 + threadIdx.x;
  if (e < kE) {
    int d = dst[e];
    int p = atomicAdd(&pos[d], 1);
    csr_src[p] = src[e];
  }
}

// ---------------------------------------------------------------- GEMM layer 1
__global__ __launch_bounds__(256) void gemm1_kernel(
    const float* __restrict__ A, const float* __restrict__ W,
    const float* __restrict__ dis, __hip_bfloat16* __restrict__ out) {
  constexpr int BC = 128, NJ = 8, WF4 = 4;
  __shared__ float xs[64 * 33];
  __shared__ float wsh[32 * BC];
  int tid = threadIdx.x;
  int tx = tid & 15, ty = tid >> 4;
  int r0 = blockIdx.x * 64;
  float acc[4][NJ];
#pragma unroll
  for (int r = 0; r < 4; r++)
#pragma unroll
    for (int j = 0; j < NJ; j++) acc[r][j] = 0.f;

  for (int kb = 0; kb < 128; kb += 32) {
    __syncthreads();
#pragma unroll
    for (int q = 0; q < 2; q++) {
      int f = tid + q * 256;
      int row = f >> 3, kq = f & 7;
      float4 v = *(const float4*)(A + (size_t)(r0 + row) * 128 + kb + kq * 4);
      int bb = row * 33 + kq * 4;
      xs[bb + 0] = v.x; xs[bb + 1] = v.y; xs[bb + 2] = v.z; xs[bb + 3] = v.w;
    }
#pragma unroll
    for (int q = 0; q < WF4; q++) {
      int f = tid + q * 256;
      int k = f / (BC / 4), cq = f % (BC / 4);
      *(float4*)&wsh[k * BC + cq * 4] =
          *(const float4*)(W + (size_t)(kb + k) * BC + cq * 4);
    }
    __syncthreads();
#pragma unroll
    for (int kk = 0; kk < 32; kk++) {
      float av[4];
#pragma unroll
      for (int r = 0; r < 4; r++) av[r] = xs[(ty * 4 + r) * 33 + kk];
#pragma unroll
      for (int j = 0; j < NJ; j++) {
        float bv = wsh[kk * BC + tx + j * 16];
#pragma unroll
        for (int r = 0; r < 4; r++) acc[r][j] = fmaf(av[r], bv, acc[r][j]);
      }
    }
  }
#pragma unroll
  for (int r = 0; r < 4; r++) {
    int row = r0 + ty * 4 + r;
    float dr = dis[row];
#pragma unroll
    for (int j = 0; j < NJ; j++)
      out[(size_t)row * BC + tx + j * 16] = __float2bfloat16(acc[r][j] * dr);
  }
}

// ---------------------------------------------------------------- GEMM layer 2
__global__ __launch_bounds__(256) void gemm2_kernel(
    const unsigned short* __restrict__ A, const float* __restrict__ W,
    const float* __restrict__ sums, const float* __restrict__ g,
    const float* __restrict__ b, const float* __restrict__ dis,
    __hip_bfloat16* __restrict__ out) {
  constexpr int BC = 64, NJ = 4, WF4 = 2;
  __shared__ float xs[64 * 33];
  __shared__ float wsh[32 * BC];
  __shared__ float s_scl[128], s_shf[128];
  int tid = threadIdx.x;
  if (tid < 128) {
    float mean = sums[tid] / (float)kN;
    float var = sums[128 + tid] / (float)kN - mean * mean;
    float inv = rsqrtf(var + kEps);
    float sc = g[tid] * inv;
    s_scl[tid] = sc;
    s_shf[tid] = b[tid] - mean * sc;
  }
  int tx = tid & 15, ty = tid >> 4;
  int r0 = blockIdx.x * 64;
  float acc[4][NJ];
#pragma unroll
  for (int r = 0; r < 4; r++)
#pragma unroll
    for (int j = 0; j < NJ; j++) acc[r][j] = 0.f;

  for (int kb = 0; kb < 128; kb += 32) {
    __syncthreads();
    {
      int row = tid >> 2, kq = tid & 3;
      short8v v8 = *(const short8v*)(A + (size_t)(r0 + row) * 128 + kb + kq * 8);
      int bb = row * 33 + kq * 8;
#pragma unroll
      for (int j = 0; j < 8; j++) {
        int c = kb + kq * 8 + j;
        float v = bf2f((unsigned short)v8[j]);
        xs[bb + j] = fmaxf(0.f, fmaf(v, s_scl[c], s_shf[c]));
      }
    }
#pragma unroll
    for (int q = 0; q < WF4; q++) {
      int f = tid + q * 256;
      int k = f / (BC / 4), cq = f % (BC / 4);
      *(float4*)&wsh[k * BC + cq * 4] =
          *(const float4*)(W + (size_t)(kb + k) * BC + cq * 4);
    }
    __syncthreads();
#pragma unroll
    for (int kk = 0; kk < 32; kk++) {
      float av[4];
#pragma unroll
      for (int r = 0; r < 4; r++) av[r] = xs[(ty * 4 + r) * 33 + kk];
#pragma unroll
      for (int j = 0; j < NJ; j++) {
        float bv = wsh[kk * BC + tx + j * 16];
#pragma unroll
        for (int r = 0; r < 4; r++) acc[r][j] = fmaf(av[r], bv, acc[r][j]);
      }
    }
  }
#pragma unroll
  for (int r = 0; r < 4; r++) {
    int row = r0 + ty * 4 + r;
    float dr = dis[row];
#pragma unroll
    for (int j = 0; j < NJ; j++)
      out[(size_t)row * BC + tx + j * 16] = __float2bfloat16(acc[r][j] * dr);
  }
}

// ---------------------------------------------------------------- aggregation
// agg1: C=128. One wave per node; 4 lane-groups of 16; each group gathers a
// whole 256 B row as short8 (16 B/lane, 1 KB/wave-instr); shfl-xor reduce.
__global__ __launch_bounds__(256) void agg1_kernel(const unsigned short* __restrict__ hs,
    const int* __restrict__ csr_src, const int* __restrict__ offsets,
    const int* __restrict__ counts, const float* __restrict__ dis,
    unsigned short* __restrict__ t1) {
  int tid = threadIdx.x;
  int wv = tid >> 6, lane = tid & 63;
  int d = blockIdx.x * 4 + wv;
  int g = lane >> 4, l = lane & 15;
  float acc[8];
  if (g == 0) {
    short8v v = *(const short8v*)(hs + (size_t)d * 128 + l * 8);
#pragma unroll
    for (int j = 0; j < 8; j++) acc[j] = bf2f((unsigned short)v[j]);
  } else {
#pragma unroll
    for (int j = 0; j < 8; j++) acc[j] = 0.f;
  }
  int s0 = offsets[d], n = counts[d];
  int i = g;
  for (; i + 4 < n; i += 8) {
    int sa = csr_src[s0 + i];
    int sb = csr_src[s0 + i + 4];
    short8v va = *(const short8v*)(hs + (size_t)sa * 128 + l * 8);
    short8v vb = *(const short8v*)(hs + (size_t)sb * 128 + l * 8);
#pragma unroll
    for (int j = 0; j < 8; j++) acc[j] += bf2f((unsigned short)va[j]);
#pragma unroll
    for (int j = 0; j < 8; j++) acc[j] += bf2f((unsigned short)vb[j]);
  }
  if (i < n) {
    int sa = csr_src[s0 + i];
    short8v va = *(const short8v*)(hs + (size_t)sa * 128 + l * 8);
#pragma unroll
    for (int j = 0; j < 8; j++) acc[j] += bf2f((unsigned short)va[j]);
  }
#pragma unroll
  for (int j = 0; j < 8; j++) {
    acc[j] += __shfl_xor(acc[j], 16, 64);
    acc[j] += __shfl_xor(acc[j], 32, 64);
  }
  if (g == 0) {
    float dd = dis[d];
    short8v o;
#pragma unroll
    for (int j = 0; j < 8; j++) o[j] = (short)f2bf(acc[j] * dd);
    *(short8v*)(t1 + (size_t)d * 128 + l * 8) = o;
  }
}

// agg2: C=64. One wave per node; 8 lane-groups of 8; 128 B rows; fp32 out.
__global__ __launch_bounds__(256) void agg2_kernel(const unsigned short* __restrict__ hs,
    const int* __restrict__ csr_src, const int* __restrict__ offsets,
    const int* __restrict__ counts, const float* __restrict__ dis,
    float* __restrict__ t2) {
  int tid = threadIdx.x;
  int wv = tid >> 6, lane = tid & 63;
  int d = blockIdx.x * 4 + wv;
  int g = lane >> 3, l = lane & 7;
  float acc[8];
  if (g == 0) {
    short8v v = *(const short8v*)(hs + (size_t)d * 64 + l * 8);
#pragma unroll
    for (int j = 0; j < 8; j++) acc[j] = bf2f((unsigned short)v[j]);
  } else {
#pragma unroll
    for (int j = 0; j < 8; j++) acc[j] = 0.f;
  }
  int s0 = offsets[d], n = counts[d];
  int i = g;
  for (; i + 8 < n; i += 16) {
    int sa = csr_src[s0 + i];
    int sb = csr_src[s0 + i + 8];
    short8v va = *(const short8v*)(hs + (size_t)sa * 64 + l * 8);
    short8v vb = *(const short8v*)(hs + (size_t)sb * 64 + l * 8);
#pragma unroll
    for (int j = 0; j < 8; j++) acc[j] += bf2f((unsigned short)va[j]);
#pragma unroll
    for (int j = 0; j < 8; j++) acc[j] += bf2f((unsigned short)vb[j]);
  }
  if (i < n) {
    int sa = csr_src[s0 + i];
    short8v va = *(const short8v*)(hs + (size_t)sa * 64 + l * 8);
#pragma unroll
    for (int j = 0; j < 8; j++) acc[j] += bf2f((unsigned short)va[j]);
  }
#pragma unroll
  for (int j = 0; j < 8; j++) {
    acc[j] += __shfl_xor(acc[j], 8, 64);
    acc[j] += __shfl_xor(acc[j], 16, 64);
    acc[j] += __shfl_xor(acc[j], 32, 64);
  }
  if (g == 0) {
    float dd = dis[d];
    float* o = t2 + (size_t)d * 64 + l * 8;
    f32x4 o0 = {acc[0] * dd, acc[1] * dd, acc[2] * dd, acc[3] * dd};
    f32x4 o1 = {acc[4] * dd, acc[5] * dd, acc[6] * dd, acc[7] * dd};
    *(f32x4*)o = o0;
    *(f32x4*)(o + 4) = o1;
  }
}

// ---------------------------------------------------------------- BN stats
template <int C, bool BF16>
__global__ __launch_bounds__(256) void stats_kernel(const void* __restrict__ t,
                                                    float* __restrict__ sums) {
  constexpr int RP = 256 / C;
  int c = threadIdx.x % C;
  int rr = threadIdx.x / C;
  float s = 0.f, s2 = 0.f;
  for (int r = blockIdx.x * RP + rr; r < kN; r += gridDim.x * RP) {
    float v;
    if constexpr (BF16) v = bf2f(((const unsigned short*)t)[(size_t)r * C + c]);
    else v = ((const float*)t)[(size_t)r * C + c];
    s += v;
    s2 += v * v;
  }
  atomicAdd(&sums[c], s);
  atomicAdd(&sums[C + c], s2);
}

// ---------------------------------------------------------------- z + heads (fused)
// BN2 finalize per-block; z kept in registers for heads; only zb (bf16) stored.
__global__ __launch_bounds__(256) void zheads_kernel(const float* __restrict__ t2,
    const float* __restrict__ sums, const float* __restrict__ gg,
    const float* __restrict__ bb2,
    const float* __restrict__ wbin, const float* __restrict__ bbin,
    const float* __restrict__ wmc, const float* __restrict__ bmc,
    const float* __restrict__ wcont, const float* __restrict__ bcont,
    float* __restrict__ out0, unsigned short* __restrict__ zb) {
  __shared__ float wT[30 * 64];
  __shared__ float bias[32];
  __shared__ float s_scl[64], s_shf[64];
  int tid = threadIdx.x;
  for (int idx = tid; idx < 1920; idx += 256) {
    int j = idx >> 6, k = idx & 63;
    const float* src = (j < 10) ? wbin : (j < 20) ? wmc : wcont;
    wT[idx] = src[k * 10 + (j % 10)];
  }
  if (tid < 30)
    bias[tid] = (tid < 10) ? bbin[tid] : (tid < 20) ? bmc[tid - 10] : bcont[tid - 20];
  if (tid < 64) {
    float mean = sums[tid] / (float)kN;
    float var = sums[64 + tid] / (float)kN - mean * mean;
    float inv = rsqrtf(var + kEps);
    float sc = gg[tid] * inv;
    s_scl[tid] = sc;
    s_shf[tid] = bb2[tid] - mean * sc;
  }
  __syncthreads();
  int n = blockIdx.x * 256 + tid;
  float zr[64];
  const float4* t4 = (const float4*)(t2 + (size_t)n * 64);
#pragma unroll
  for (int q = 0; q < 16; q++) {
    float4 v = t4[q];
    zr[4 * q + 0] = fmaxf(0.f, fmaf(v.x, s_scl[4 * q + 0], s_shf[4 * q + 0]));
    zr[4 * q + 1] = fmaxf(0.f, fmaf(v.y, s_scl[4 * q + 1], s_shf[4 * q + 1]));
    zr[4 * q + 2] = fmaxf(0.f, fmaf(v.z, s_scl[4 * q + 2], s_shf[4 * q + 2]));
    zr[4 * q + 3] = fmaxf(0.f, fmaf(v.w, s_scl[4 * q + 3], s_shf[4 * q + 3]));
  }
  unsigned short* zrow = zb + (size_t)n * 64;
#pragma unroll
  for (int q = 0; q < 8; q++) {
    short8v o;
#pragma unroll
    for (int j = 0; j < 8; j++) o[j] = (short)f2bf(zr[q * 8 + j]);
    *(short8v*)(zrow + q * 8) = o;
  }
  float acc[30];
#pragma unroll
  for (int j = 0; j < 30; j++) {
    float s = bias[j];
#pragma unroll
    for (int kc = 0; kc < 16; kc++) {
      f32x4 wv = *(const f32x4*)&wT[j * 64 + kc * 4];
      s = fmaf(zr[4 * kc + 0], wv.x, s);
      s = fmaf(zr[4 * kc + 1], wv.y, s);
      s = fmaf(zr[4 * kc + 2], wv.z, s);
      s = fmaf(zr[4 * kc + 3], wv.w, s);
    }
    acc[j] = s;
  }
  float* o = out0 + (size_t)n * 30;
#pragma unroll
  for (int j = 0; j < 10; j++) o[j] = 1.f / (1.f + expf(-acc[j]));
  float m1 = fmaxf(fmaxf(acc[10], acc[11]), fmaxf(acc[12], acc[13]));
  float e1[4], s1 = 0.f;
#pragma unroll
  for (int j = 0; j < 4; j++) { e1[j] = expf(acc[10 + j] - m1); s1 += e1[j]; }
#pragma unroll
  for (int j = 0; j < 4; j++) o[10 + j] = e1[j] / s1;
  float m2 = acc[14];
#pragma unroll
  for (int j = 15; j < 20; j++) m2 = fmaxf(m2, acc[j]);
  float e2[6], s2 = 0.f;
#pragma unroll
  for (int j = 0; j < 6; j++) { e2[j] = expf(acc[14 + j] - m2); s2 += e2[j]; }
#pragma unroll
  for (int j = 0; j < 6; j++) o[14 + j] = e2[j] / s2;
#pragma unroll
  for (int j = 0; j < 10; j++) o[20 + j] = acc[20 + j];
}

// ---------------------------------------------------------------- adj = z z^T (bf16 MFMA)
__global__ __launch_bounds__(256) void adj_kernel(const short* __restrict__ zb,
                                                  float* __restrict__ adj) {
  __shared__ float cs[128 * 132];
  int tid = threadIdx.x;
  int wid = tid >> 6, lane = tid & 63;
  int li0 = (wid >> 1) * 64;
  int lj0 = (wid & 1) * 64;
  int i0 = blockIdx.x * 128 + li0;
  int j0 = blockIdx.y * 128 + lj0;
  int lr = lane & 15, lg = lane >> 4;
  short8v a[4][2], b[4][2];
#pragma unroll
  for (int mt = 0; mt < 4; mt++)
#pragma unroll
    for (int ks = 0; ks < 2; ks++)
      a[mt][ks] = *(const short8v*)(zb + (size_t)(i0 + mt * 16 + lr) * 64 + ks * 32 + lg * 8);
#pragma unroll
  for (int nt = 0; nt < 4; nt++)
#pragma unroll
    for (int ks = 0; ks < 2; ks++)
      b[nt][ks] = *(const short8v*)(zb + (size_t)(j0 + nt * 16 + lr) * 64 + ks * 32 + lg * 8);
  f32x4 acc[4][4];
#pragma unroll
  for (int mt = 0; mt < 4; mt++)
#pragma unroll
    for (int nt = 0; nt < 4; nt++) {
      f32x4 zz = {0.f, 0.f, 0.f, 0.f};
      acc[mt][nt] = zz;
    }
#pragma unroll
  for (int ks = 0; ks < 2; ks++)
#pragma unroll
    for (int mt = 0; mt < 4; mt++)
#pragma unroll
      for (int nt = 0; nt < 4; nt++)
        acc[mt][nt] = __builtin_amdgcn_mfma_f32_16x16x32_bf16(a[mt][ks], b[nt][ks],
                                                              acc[mt][nt], 0, 0, 0);
#pragma unroll
  for (int mt = 0; mt < 4; mt++)
#pragma unroll
    for (int nt = 0; nt < 4; nt++)
#pragma unroll
      for (int r = 0; r < 4; r++)
        cs[(li0 + mt * 16 + lg * 4 + r) * 132 + lj0 + nt * 16 + lr] = acc[mt][nt][r];
  __syncthreads();
  int row = tid >> 5;
  int c4 = tid & 31;
  size_t gbase = (size_t)(blockIdx.x * 128 + row) * kN + blockIdx.y * 128 + c4 * 4;
  const float* lbase = &cs[row * 132 + c4 * 4];
#pragma unroll
  for (int it = 0; it < 16; it++) {
    f32x4 v = *(const f32x4*)(lbase + it * 8 * 132);
    *(f32x4*)(adj + gbase + (size_t)it * 8 * kN) = v;
  }
}

// ---------------------------------------------------------------- edge features (MFMA)
// Per wave-tile: 16 edges x 16 outs, K=64 per side -> 4 MFMA; result staged in
// per-wave LDS then written as 1 KB contiguous float4s (in-wave DS ordering).
__global__ __launch_bounds__(256) void edge_mfma_kernel(const short* __restrict__ zb,
    const int* __restrict__ srcs, const int* __restrict__ dsts,
    const short* __restrict__ wfr, const float* __restrict__ be,
    float* __restrict__ eout) {
  __shared__ float es[4][256];
  int tid = threadIdx.x;
  int wv = tid >> 6, lane = tid & 63;
  int gw = blockIdx.x * 4 + wv;          // 4096 waves total
  int lr = lane & 15, lg = lane >> 4;
  short8v bfr[4];
#pragma unroll
  for (int f = 0; f < 4; f++)
    bfr[f] = *(const short8v*)(wfr + ((size_t)f * 64 + lane) * 8);
  float bias = be[lr];
  for (int t = 0; t < 8; t++) {
    int e0 = (gw * 8 + t) * 16;
    int se = srcs[e0 + lr], de = dsts[e0 + lr];
    short8v a0 = *(const short8v*)(zb + (size_t)se * 64 + lg * 8);
    short8v a1 = *(const short8v*)(zb + (size_t)se * 64 + 32 + lg * 8);
    short8v a2 = *(const short8v*)(zb + (size_t)de * 64 + lg * 8);
    short8v a3 = *(const short8v*)(zb + (size_t)de * 64 + 32 + lg * 8);
    f32x4 acc = {0.f, 0.f, 0.f, 0.f};
    acc = __builtin_amdgcn_mfma_f32_16x16x32_bf16(a0, bfr[0], acc, 0, 0, 0);
    acc = __builtin_amdgcn_mfma_f32_16x16x32_bf16(a1, bfr[1], acc, 0, 0, 0);
    acc = __builtin_amdgcn_mfma_f32_16x16x32_bf16(a2, bfr[2], acc, 0, 0, 0);
    acc = __builtin_amdgcn_mfma_f32_16x16x32_bf16(a3, bfr[3], acc, 0, 0, 0);
#pragma unroll
    for (int r = 0; r < 4; r++)
      es[wv][(lg * 4 + r) * 16 + lr] = acc[r] + bias;
    f32x4 v = *(const f32x4*)&es[wv][lane * 4];
    *(f32x4*)(eout + (size_t)e0 * 16 + lane * 4) = v;
  }
}

// ---------------------------------------------------------------- launch
extern "C" void kernel_launch(void* const* d_in, const int* in_sizes, int n_in,
                              void* d_out, int out_size, void* d_ws, size_t ws_size,
                              hipStream_t stream) {
  const float* x      = (const float*)d_in[0];
  const int*   ei     = (const int*)d_in[1];
  const float* w1     = (const float*)d_in[3];
  const float* bn1_g  = (const float*)d_in[5];
  const float* bn1_b  = (const float*)d_in[6];
  const float* w2     = (const float*)d_in[7];
  const float* bn2_g  = (const float*)d_in[9];
  const float* bn2_b  = (const float*)d_in[10];
  const float* w_bin  = (const float*)d_in[11];
  const float* b_bin  = (const float*)d_in[12];
  const float* w_mc   = (const float*)d_in[13];
  const float* b_mc   = (const float*)d_in[14];
  const float* w_cont = (const float*)d_in[15];
  const float* b_cont = (const float*)d_in[16];
  const float* w_edge = (const float*)d_in[17];
  const float* b_edge = (const float*)d_in[18];

  float* out0 = (float*)d_out;
  float* adj  = out0 + (size_t)kN * 30;
  float* eout = adj + (size_t)kN * kN;

  char* wp = (char*)d_ws;
  auto alloc = [&](size_t bytes) {
    char* p = wp;
    wp += (bytes + 255) & ~(size_t)255;
    return p;
  };
  int*   counts  = (int*)alloc((size_t)kN * 4);
  int*   offsets = (int*)alloc((size_t)kN * 4);
  int*   pos     = (int*)alloc((size_t)kN * 4);
  int*   csr_src = (int*)alloc((size_t)kE * 4);
  float* dis     = (float*)alloc((size_t)kN * 4);
  float* sums1   = (float*)alloc(256 * 4);
  float* sums2   = (float*)alloc(128 * 4);
  unsigned short* hs1 = (unsigned short*)alloc((size_t)kN * 128 * 2);
  unsigned short* t1  = (unsigned short*)alloc((size_t)kN * 128 * 2);
  unsigned short* hs2 = (unsigned short*)alloc((size_t)kN * 64 * 2);
  float* t2      = (float*)alloc((size_t)kN * 64 * 4);
  unsigned short* zb  = (unsigned short*)alloc((size_t)kN * 64 * 2);
  __hip_bfloat16* wfr = (__hip_bfloat16*)alloc(2048 * 2);

  const int* esrc = ei;
  const int* edst = ei + kE;

  zero_kernel<<<dim3(64), dim3(256), 0, stream>>>(counts, sums1, sums2, w_edge, wfr);
  hist_kernel<<<dim3(2048), dim3(256), 0, stream>>>(edst, counts);
  scan_kernel<<<dim3(1), dim3(1024), 0, stream>>>(counts, offsets, pos, dis);
  fill_kernel<<<dim3(2048), dim3(256), 0, stream>>>(esrc, edst, pos, csr_src);

  gemm1_kernel<<<dim3(kN / 64), dim3(256), 0, stream>>>(
      x, w1, dis, (__hip_bfloat16*)hs1);
  agg1_kernel<<<dim3(kN / 4), dim3(256), 0, stream>>>(
      hs1, csr_src, offsets, counts, dis, t1);
  stats_kernel<128, true><<<dim3(256), dim3(256), 0, stream>>>(t1, sums1);

  gemm2_kernel<<<dim3(kN / 64), dim3(256), 0, stream>>>(
      t1, w2, sums1, bn1_g, bn1_b, dis, (__hip_bfloat16*)hs2);
  agg2_kernel<<<dim3(kN / 4), dim3(256), 0, stream>>>(
      hs2, csr_src, offsets, counts, dis, t2);
  stats_kernel<64, false><<<dim3(256), dim3(256), 0, stream>>>(t2, sums2);

  zheads_kernel<<<dim3(kN / 256), dim3(256), 0, stream>>>(
      t2, sums2, bn2_g, bn2_b, w_bin, b_bin, w_mc, b_mc, w_cont, b_cont, out0, zb);

  adj_kernel<<<dim3(kN / 128, kN / 128), dim3(256), 0, stream>>>((const short*)zb, adj);
  edge_mfma_kernel<<<dim3(1024), dim3(256), 0, stream>>>(
      (const short*)zb, esrc, edst, (const short*)wfr, b_edge, eout);
}